// Round 1
// baseline (544.435 us; speedup 1.0000x reference)
//
#include <hip/hip_runtime.h>

// ---------------------------------------------------------------------------
// 2-layer GCN + mean-pool + MLP head, fp32 correctness-first version.
// Pipeline: deg hist -> dinv -> CSR build (scan+fill) -> GEMM1 (scaled) ->
//           AGG1 -> GEMM2 (scaled) -> AGG2 -> POOL -> HEAD
// ---------------------------------------------------------------------------

#define HID 128

__global__ __launch_bounds__(256) void hist_k(const int* __restrict__ dst,
                                              int* __restrict__ cnt, int E) {
  int i = blockIdx.x * 256 + threadIdx.x;
  if (i < E) atomicAdd(&cnt[dst[i]], 1);
}

__global__ __launch_bounds__(256) void dinv_k(const int* __restrict__ cnt,
                                              float* __restrict__ dinv, int N) {
  int i = blockIdx.x * 256 + threadIdx.x;
  if (i < N) dinv[i] = rsqrtf((float)(cnt[i] + 1));  // +1 self-loop
}

// --- 3-kernel exclusive scan over per-node in-degree ---
__global__ __launch_bounds__(256) void scan_bsum(const int* __restrict__ cnt,
                                                 int* __restrict__ bsum, int n) {
  __shared__ int sm[256];
  int i = blockIdx.x * 256 + threadIdx.x;
  int v = (i < n) ? cnt[i] : 0;
  sm[threadIdx.x] = v;
  __syncthreads();
  for (int off = 128; off > 0; off >>= 1) {
    if (threadIdx.x < off) sm[threadIdx.x] += sm[threadIdx.x + off];
    __syncthreads();
  }
  if (threadIdx.x == 0) bsum[blockIdx.x] = sm[0];
}

__global__ __launch_bounds__(256) void scan_bsum_ex(int* bsum, int nb) {
  // single block, nb <= 256
  __shared__ int sm[256];
  int t = threadIdx.x;
  int v = (t < nb) ? bsum[t] : 0;
  sm[t] = v;
  __syncthreads();
  for (int off = 1; off < 256; off <<= 1) {
    int add = (t >= off) ? sm[t - off] : 0;
    __syncthreads();
    sm[t] += add;
    __syncthreads();
  }
  if (t < nb) bsum[t] = sm[t] - v;  // exclusive
}

__global__ __launch_bounds__(256) void scan_offsets(const int* __restrict__ cnt,
                                                    const int* __restrict__ bsum,
                                                    int* __restrict__ offs, int n) {
  __shared__ int sm[256];
  int i = blockIdx.x * 256 + threadIdx.x;
  int t = threadIdx.x;
  int v = (i < n) ? cnt[i] : 0;
  sm[t] = v;
  __syncthreads();
  for (int off = 1; off < 256; off <<= 1) {
    int add = (t >= off) ? sm[t - off] : 0;
    __syncthreads();
    sm[t] += add;
    __syncthreads();
  }
  int base = bsum[blockIdx.x];
  if (i < n) offs[i] = base + sm[t] - v;
  if (i == n - 1) offs[n] = base + sm[t];  // total
}

__global__ __launch_bounds__(256) void fill_k(const int* __restrict__ src,
                                              const int* __restrict__ dst,
                                              const int* __restrict__ offs,
                                              int* __restrict__ cur,
                                              int* __restrict__ csr, int E) {
  int i = blockIdx.x * 256 + threadIdx.x;
  if (i >= E) return;
  int d = dst[i];
  int p = offs[d] + atomicAdd(&cur[d], 1);
  csr[p] = src[i];
}

// --- fp32 GEMM: C[M][128] = (A[M][K] @ W[K][128]) * scale[row] ---
// 128x128 tile, 256 threads, 8x8 acc/thread, K-chunk 32.
template <int K>
__global__ __launch_bounds__(256) void gemm_k(const float* __restrict__ A,
                                              const float* __restrict__ W,
                                              const float* __restrict__ scale,
                                              float* __restrict__ C, int M) {
  __shared__ float As[128][34];  // pad 34: a-reads spread banks, float2-friendly
  __shared__ float Ws[32][HID];
  const int tid = threadIdx.x;
  const int tn = tid & 15;   // 16 col groups: cols tn*4..+3 and 64+tn*4..+3
  const int tm = tid >> 4;   // 16 row groups of 8 rows
  const int row0 = blockIdx.x * 128;

  float acc[8][8];
#pragma unroll
  for (int i = 0; i < 8; ++i)
#pragma unroll
    for (int j = 0; j < 8; ++j) acc[i][j] = 0.f;

  for (int k0 = 0; k0 < K; k0 += 32) {
    // stage W chunk [32][128]: 1024 float4
#pragma unroll
    for (int t = 0; t < 4; ++t) {
      int f = tid + t * 256;
      int kk = f >> 5;
      int cc = (f & 31) << 2;
      *(float4*)&Ws[kk][cc] = *(const float4*)&W[(size_t)(k0 + kk) * HID + cc];
    }
    // stage A chunk [128 rows][32 k]: float4 global read, 4 scalar LDS writes
#pragma unroll
    for (int t = 0; t < 4; ++t) {
      int f = tid + t * 256;
      int rr = f >> 3;
      int kc = (f & 7) << 2;
      int gr = row0 + rr;
      float4 v = make_float4(0.f, 0.f, 0.f, 0.f);
      if (gr < M) v = *(const float4*)&A[(size_t)gr * K + k0 + kc];
      As[rr][kc + 0] = v.x;
      As[rr][kc + 1] = v.y;
      As[rr][kc + 2] = v.z;
      As[rr][kc + 3] = v.w;
    }
    __syncthreads();
#pragma unroll 4
    for (int kk = 0; kk < 32; kk += 2) {
      float2 a2[8];
#pragma unroll
      for (int i = 0; i < 8; ++i) a2[i] = *(const float2*)&As[tm * 8 + i][kk];
      float4 b00 = *(const float4*)&Ws[kk][tn * 4];
      float4 b01 = *(const float4*)&Ws[kk][64 + tn * 4];
      float4 b10 = *(const float4*)&Ws[kk + 1][tn * 4];
      float4 b11 = *(const float4*)&Ws[kk + 1][64 + tn * 4];
      float b0[8] = {b00.x, b00.y, b00.z, b00.w, b01.x, b01.y, b01.z, b01.w};
      float b1[8] = {b10.x, b10.y, b10.z, b10.w, b11.x, b11.y, b11.z, b11.w};
#pragma unroll
      for (int i = 0; i < 8; ++i) {
#pragma unroll
        for (int j = 0; j < 8; ++j) {
          acc[i][j] = fmaf(a2[i].x, b0[j], acc[i][j]);
          acc[i][j] = fmaf(a2[i].y, b1[j], acc[i][j]);
        }
      }
    }
    __syncthreads();
  }
#pragma unroll
  for (int i = 0; i < 8; ++i) {
    int r = row0 + tm * 8 + i;
    if (r < M) {
      float s = scale[r];
      float4 o0, o1;
      o0.x = acc[i][0] * s; o0.y = acc[i][1] * s;
      o0.z = acc[i][2] * s; o0.w = acc[i][3] * s;
      o1.x = acc[i][4] * s; o1.y = acc[i][5] * s;
      o1.z = acc[i][6] * s; o1.w = acc[i][7] * s;
      *(float4*)&C[(size_t)r * HID + tn * 4] = o0;
      *(float4*)&C[(size_t)r * HID + 64 + tn * 4] = o1;
    }
  }
}

// --- aggregation: out[v] = relu(dinv[v]*(sum_{u in in(v)} Hs[u] + Hs[v]) + b)
// Hs is already scaled by dinv[src] in the GEMM epilogue.
__global__ __launch_bounds__(256) void agg_k(const float* __restrict__ Hs,
                                             const int* __restrict__ offs,
                                             const int* __restrict__ csr,
                                             const float* __restrict__ dinv,
                                             const float* __restrict__ bias,
                                             float* __restrict__ out, int N) {
  int v = blockIdx.x * 2 + (threadIdx.x >> 7);
  int j = threadIdx.x & 127;
  if (v >= N) return;
  int s = offs[v];
  int e = offs[v + 1];
  float acc = Hs[(size_t)v * HID + j];  // self-loop term (pre-scaled)
  for (int p = s; p < e; ++p) {
    int u = csr[p];
    acc += Hs[(size_t)u * HID + j];
  }
  out[(size_t)v * HID + j] = fmaxf(fmaf(acc, dinv[v], bias[j]), 0.f);
}

// --- mean pool per graph (node_batch is sorted) ---
__global__ __launch_bounds__(256) void pool_k(const float* __restrict__ G,
                                              const int* __restrict__ batch,
                                              float* __restrict__ pooled, int n) {
  int g = blockIdx.x;
  int lo = 0, hi = n;
  while (lo < hi) { int mid = (lo + hi) >> 1; if (batch[mid] < g) lo = mid + 1; else hi = mid; }
  int start = lo;
  hi = n;
  while (lo < hi) { int mid = (lo + hi) >> 1; if (batch[mid] <= g) lo = mid + 1; else hi = mid; }
  int end = lo;
  int j = threadIdx.x & 127;
  int half = threadIdx.x >> 7;
  float acc = 0.f;
  for (int r = start + half; r < end; r += 2) acc += G[(size_t)r * HID + j];
  __shared__ float sm[256];
  sm[threadIdx.x] = acc;
  __syncthreads();
  if (half == 0) {
    float tot = sm[j] + sm[128 + j];
    float c = (float)(end - start);
    pooled[g * HID + j] = tot / fmaxf(c, 1.f);
  }
}

// --- head: fused = relu([seq|pooled] @ Wf + bf); tp = fused@Wtp+btp; pr = fused@Wp+bp
__global__ __launch_bounds__(128) void head_k(const float* __restrict__ seq,
                                              const float* __restrict__ pooled,
                                              const float* __restrict__ Wf,
                                              const float* __restrict__ bf,
                                              const float* __restrict__ Wtp,
                                              const float* __restrict__ btp,
                                              const float* __restrict__ Wp,
                                              const float* __restrict__ bp,
                                              float* __restrict__ outp,
                                              int B, int SEQ) {
  int g = blockIdx.x;
  int t = threadIdx.x;
  __shared__ float xin[512];
  __shared__ float fs[128];
  for (int i = t; i < SEQ; i += 128) xin[i] = seq[(size_t)g * SEQ + i];
  xin[SEQ + t] = pooled[g * HID + t];
  __syncthreads();
  float acc = bf[t];
#pragma unroll 8
  for (int k = 0; k < 512; ++k) acc = fmaf(xin[k], Wf[(size_t)k * HID + t], acc);
  fs[t] = fmaxf(acc, 0.f);
  __syncthreads();
  if (t == 0) {
    float a0 = btp[0], a1 = btp[1], a2 = bp[0];
    for (int k = 0; k < 128; ++k) {
      float f = fs[k];
      a0 = fmaf(f, Wtp[k * 2 + 0], a0);
      a1 = fmaf(f, Wtp[k * 2 + 1], a1);
      a2 = fmaf(f, Wp[k], a2);
    }
    outp[g * 2 + 0] = a0;
    outp[g * 2 + 1] = a1;
    outp[B * 2 + g] = a2;
  }
}

extern "C" void kernel_launch(void* const* d_in, const int* in_sizes, int n_in,
                              void* d_out, int out_size, void* d_ws, size_t ws_size,
                              hipStream_t stream) {
  const float* seq_emb = (const float*)d_in[0];
  const float* node_x  = (const float*)d_in[1];
  const int*   eidx    = (const int*)d_in[2];
  const int*   nbatch  = (const int*)d_in[3];
  const float* W1  = (const float*)d_in[4];
  const float* b1  = (const float*)d_in[5];
  const float* W2  = (const float*)d_in[6];
  const float* b2  = (const float*)d_in[7];
  const float* Wf  = (const float*)d_in[8];
  const float* bfb = (const float*)d_in[9];
  const float* Wtp = (const float*)d_in[10];
  const float* btp = (const float*)d_in[11];
  const float* Wp  = (const float*)d_in[12];
  const float* bp  = (const float*)d_in[13];

  const int N = in_sizes[3];           // 50000 nodes
  const int E = in_sizes[2] / 2;       // 600000 edges
  const int SEQ = 384;
  const int B = in_sizes[0] / SEQ;     // 64 graphs

  char* w = (char*)d_ws;
  auto alloc = [&](size_t bytes) -> void* {
    void* p = (void*)w;
    w += (bytes + 255) & ~(size_t)255;
    return p;
  };
  float* dinv   = (float*)alloc((size_t)N * 4);
  int*   deg    = (int*)alloc((size_t)N * 4);
  int*   cur    = (int*)alloc((size_t)N * 4);
  int*   offs   = (int*)alloc((size_t)(N + 1) * 4);
  int*   bsum   = (int*)alloc(1024);
  int*   csr    = (int*)alloc((size_t)E * 4);
  float* bufA   = (float*)alloc((size_t)N * HID * 4);
  float* bufB   = (float*)alloc((size_t)N * HID * 4);
  float* pooled = (float*)alloc((size_t)B * HID * 4);

  const int* srcp = eidx;
  const int* dstp = eidx + E;

  hipMemsetAsync(deg, 0, (size_t)N * 4, stream);
  hipMemsetAsync(cur, 0, (size_t)N * 4, stream);

  int gE = (E + 255) / 256;
  int gN = (N + 255) / 256;  // 196 <= 256 (required by scan_bsum_ex)
  hist_k<<<gE, 256, 0, stream>>>(dstp, deg, E);
  dinv_k<<<gN, 256, 0, stream>>>(deg, dinv, N);
  scan_bsum<<<gN, 256, 0, stream>>>(deg, bsum, N);
  scan_bsum_ex<<<1, 256, 0, stream>>>(bsum, gN);
  scan_offsets<<<gN, 256, 0, stream>>>(deg, bsum, offs, N);
  fill_k<<<gE, 256, 0, stream>>>(srcp, dstp, offs, cur, csr, E);

  int gG = (N + 127) / 128;
  gemm_k<384><<<gG, 256, 0, stream>>>(node_x, W1, dinv, bufA, N);
  agg_k<<<(N + 1) / 2, 256, 0, stream>>>(bufA, offs, csr, dinv, b1, bufB, N);
  gemm_k<128><<<gG, 256, 0, stream>>>(bufB, W2, dinv, bufA, N);
  agg_k<<<(N + 1) / 2, 256, 0, stream>>>(bufA, offs, csr, dinv, b2, bufB, N);
  pool_k<<<B, 256, 0, stream>>>(bufB, nbatch, pooled, N);
  head_k<<<B, 128, 0, stream>>>(seq_emb, pooled, Wf, bfb, Wtp, btp, Wp, bp,
                                (float*)d_out, B, SEQ);
}

// Round 2
// 409.490 us; speedup vs baseline: 1.3295x; 1.3295x over previous
//
#include <hip/hip_runtime.h>

// ---------------------------------------------------------------------------
// 2-layer GCN + mean-pool + MLP head, fp32.
// Pipeline: deg hist -> dinv -> CSR build (scan+fill) -> GEMM1 (scaled) ->
//           AGG1 -> GEMM2 (scaled) -> AGG2 -> POOL -> HEAD
// R2: agg_k rewritten for MLP: 32 lanes/node, float4/lane, edge unroll x4.
// ---------------------------------------------------------------------------

#define HID 128

__global__ __launch_bounds__(256) void hist_k(const int* __restrict__ dst,
                                              int* __restrict__ cnt, int E) {
  int i = blockIdx.x * 256 + threadIdx.x;
  if (i < E) atomicAdd(&cnt[dst[i]], 1);
}

__global__ __launch_bounds__(256) void dinv_k(const int* __restrict__ cnt,
                                              float* __restrict__ dinv, int N) {
  int i = blockIdx.x * 256 + threadIdx.x;
  if (i < N) dinv[i] = rsqrtf((float)(cnt[i] + 1));  // +1 self-loop
}

// --- 3-kernel exclusive scan over per-node in-degree ---
__global__ __launch_bounds__(256) void scan_bsum(const int* __restrict__ cnt,
                                                 int* __restrict__ bsum, int n) {
  __shared__ int sm[256];
  int i = blockIdx.x * 256 + threadIdx.x;
  int v = (i < n) ? cnt[i] : 0;
  sm[threadIdx.x] = v;
  __syncthreads();
  for (int off = 128; off > 0; off >>= 1) {
    if (threadIdx.x < off) sm[threadIdx.x] += sm[threadIdx.x + off];
    __syncthreads();
  }
  if (threadIdx.x == 0) bsum[blockIdx.x] = sm[0];
}

__global__ __launch_bounds__(256) void scan_bsum_ex(int* bsum, int nb) {
  // single block, nb <= 256
  __shared__ int sm[256];
  int t = threadIdx.x;
  int v = (t < nb) ? bsum[t] : 0;
  sm[t] = v;
  __syncthreads();
  for (int off = 1; off < 256; off <<= 1) {
    int add = (t >= off) ? sm[t - off] : 0;
    __syncthreads();
    sm[t] += add;
    __syncthreads();
  }
  if (t < nb) bsum[t] = sm[t] - v;  // exclusive
}

__global__ __launch_bounds__(256) void scan_offsets(const int* __restrict__ cnt,
                                                    const int* __restrict__ bsum,
                                                    int* __restrict__ offs, int n) {
  __shared__ int sm[256];
  int i = blockIdx.x * 256 + threadIdx.x;
  int t = threadIdx.x;
  int v = (i < n) ? cnt[i] : 0;
  sm[t] = v;
  __syncthreads();
  for (int off = 1; off < 256; off <<= 1) {
    int add = (t >= off) ? sm[t - off] : 0;
    __syncthreads();
    sm[t] += add;
    __syncthreads();
  }
  int base = bsum[blockIdx.x];
  if (i < n) offs[i] = base + sm[t] - v;
  if (i == n - 1) offs[n] = base + sm[t];  // total
}

__global__ __launch_bounds__(256) void fill_k(const int* __restrict__ src,
                                              const int* __restrict__ dst,
                                              const int* __restrict__ offs,
                                              int* __restrict__ cur,
                                              int* __restrict__ csr, int E) {
  int i = blockIdx.x * 256 + threadIdx.x;
  if (i >= E) return;
  int d = dst[i];
  int p = offs[d] + atomicAdd(&cur[d], 1);
  csr[p] = src[i];
}

// --- fp32 GEMM: C[M][128] = (A[M][K] @ W[K][128]) * scale[row] ---
// 128x128 tile, 256 threads, 8x8 acc/thread, K-chunk 32.
template <int K>
__global__ __launch_bounds__(256) void gemm_k(const float* __restrict__ A,
                                              const float* __restrict__ W,
                                              const float* __restrict__ scale,
                                              float* __restrict__ C, int M) {
  __shared__ float As[128][34];  // pad 34: a-reads spread banks, float2-friendly
  __shared__ float Ws[32][HID];
  const int tid = threadIdx.x;
  const int tn = tid & 15;   // 16 col groups: cols tn*4..+3 and 64+tn*4..+3
  const int tm = tid >> 4;   // 16 row groups of 8 rows
  const int row0 = blockIdx.x * 128;

  float acc[8][8];
#pragma unroll
  for (int i = 0; i < 8; ++i)
#pragma unroll
    for (int j = 0; j < 8; ++j) acc[i][j] = 0.f;

  for (int k0 = 0; k0 < K; k0 += 32) {
    // stage W chunk [32][128]: 1024 float4
#pragma unroll
    for (int t = 0; t < 4; ++t) {
      int f = tid + t * 256;
      int kk = f >> 5;
      int cc = (f & 31) << 2;
      *(float4*)&Ws[kk][cc] = *(const float4*)&W[(size_t)(k0 + kk) * HID + cc];
    }
    // stage A chunk [128 rows][32 k]: float4 global read, 4 scalar LDS writes
#pragma unroll
    for (int t = 0; t < 4; ++t) {
      int f = tid + t * 256;
      int rr = f >> 3;
      int kc = (f & 7) << 2;
      int gr = row0 + rr;
      float4 v = make_float4(0.f, 0.f, 0.f, 0.f);
      if (gr < M) v = *(const float4*)&A[(size_t)gr * K + k0 + kc];
      As[rr][kc + 0] = v.x;
      As[rr][kc + 1] = v.y;
      As[rr][kc + 2] = v.z;
      As[rr][kc + 3] = v.w;
    }
    __syncthreads();
#pragma unroll 4
    for (int kk = 0; kk < 32; kk += 2) {
      float2 a2[8];
#pragma unroll
      for (int i = 0; i < 8; ++i) a2[i] = *(const float2*)&As[tm * 8 + i][kk];
      float4 b00 = *(const float4*)&Ws[kk][tn * 4];
      float4 b01 = *(const float4*)&Ws[kk][64 + tn * 4];
      float4 b10 = *(const float4*)&Ws[kk + 1][tn * 4];
      float4 b11 = *(const float4*)&Ws[kk + 1][64 + tn * 4];
      float b0[8] = {b00.x, b00.y, b00.z, b00.w, b01.x, b01.y, b01.z, b01.w};
      float b1[8] = {b10.x, b10.y, b10.z, b10.w, b11.x, b11.y, b11.z, b11.w};
#pragma unroll
      for (int i = 0; i < 8; ++i) {
#pragma unroll
        for (int j = 0; j < 8; ++j) {
          acc[i][j] = fmaf(a2[i].x, b0[j], acc[i][j]);
          acc[i][j] = fmaf(a2[i].y, b1[j], acc[i][j]);
        }
      }
    }
    __syncthreads();
  }
#pragma unroll
  for (int i = 0; i < 8; ++i) {
    int r = row0 + tm * 8 + i;
    if (r < M) {
      float s = scale[r];
      float4 o0, o1;
      o0.x = acc[i][0] * s; o0.y = acc[i][1] * s;
      o0.z = acc[i][2] * s; o0.w = acc[i][3] * s;
      o1.x = acc[i][4] * s; o1.y = acc[i][5] * s;
      o1.z = acc[i][6] * s; o1.w = acc[i][7] * s;
      *(float4*)&C[(size_t)r * HID + tn * 4] = o0;
      *(float4*)&C[(size_t)r * HID + 64 + tn * 4] = o1;
    }
  }
}

// --- aggregation: out[v] = relu(dinv[v]*(sum_{u in in(v)} Hs[u] + Hs[v]) + b)
// Hs pre-scaled by dinv[src]. One node per 32-lane group, float4 per lane,
// edge loop unrolled x4 for memory-level parallelism (latency-bound gather).
__global__ __launch_bounds__(256) void agg_k(const float4* __restrict__ Hs4,
                                             const int* __restrict__ offs,
                                             const int* __restrict__ csr,
                                             const float* __restrict__ dinv,
                                             const float4* __restrict__ bias4,
                                             float4* __restrict__ out4, int N) {
  int grp = threadIdx.x >> 5;          // 8 groups of 32 lanes
  int lane = threadIdx.x & 31;         // lane owns 4 consecutive floats
  int v = blockIdx.x * 8 + grp;
  if (v >= N) return;
  int s = offs[v];
  int e = offs[v + 1];
  float4 acc = Hs4[(size_t)v * 32 + lane];  // self-loop term (pre-scaled)
  int p = s;
  for (; p + 4 <= e; p += 4) {
    int u0 = csr[p + 0];
    int u1 = csr[p + 1];
    int u2 = csr[p + 2];
    int u3 = csr[p + 3];
    float4 x0 = Hs4[(size_t)u0 * 32 + lane];
    float4 x1 = Hs4[(size_t)u1 * 32 + lane];
    float4 x2 = Hs4[(size_t)u2 * 32 + lane];
    float4 x3 = Hs4[(size_t)u3 * 32 + lane];
    acc.x += (x0.x + x1.x) + (x2.x + x3.x);
    acc.y += (x0.y + x1.y) + (x2.y + x3.y);
    acc.z += (x0.z + x1.z) + (x2.z + x3.z);
    acc.w += (x0.w + x1.w) + (x2.w + x3.w);
  }
  for (; p < e; ++p) {
    int u = csr[p];
    float4 x = Hs4[(size_t)u * 32 + lane];
    acc.x += x.x; acc.y += x.y; acc.z += x.z; acc.w += x.w;
  }
  float dv = dinv[v];
  float4 b = bias4[lane];
  float4 o;
  o.x = fmaxf(fmaf(acc.x, dv, b.x), 0.f);
  o.y = fmaxf(fmaf(acc.y, dv, b.y), 0.f);
  o.z = fmaxf(fmaf(acc.z, dv, b.z), 0.f);
  o.w = fmaxf(fmaf(acc.w, dv, b.w), 0.f);
  out4[(size_t)v * 32 + lane] = o;
}

// --- mean pool per graph (node_batch is sorted) ---
__global__ __launch_bounds__(256) void pool_k(const float* __restrict__ G,
                                              const int* __restrict__ batch,
                                              float* __restrict__ pooled, int n) {
  int g = blockIdx.x;
  int lo = 0, hi = n;
  while (lo < hi) { int mid = (lo + hi) >> 1; if (batch[mid] < g) lo = mid + 1; else hi = mid; }
  int start = lo;
  hi = n;
  while (lo < hi) { int mid = (lo + hi) >> 1; if (batch[mid] <= g) lo = mid + 1; else hi = mid; }
  int end = lo;
  int j = threadIdx.x & 127;
  int half = threadIdx.x >> 7;
  float acc = 0.f;
  for (int r = start + half; r < end; r += 2) acc += G[(size_t)r * HID + j];
  __shared__ float sm[256];
  sm[threadIdx.x] = acc;
  __syncthreads();
  if (half == 0) {
    float tot = sm[j] + sm[128 + j];
    float c = (float)(end - start);
    pooled[g * HID + j] = tot / fmaxf(c, 1.f);
  }
}

// --- head: fused = relu([seq|pooled] @ Wf + bf); tp = fused@Wtp+btp; pr = fused@Wp+bp
__global__ __launch_bounds__(128) void head_k(const float* __restrict__ seq,
                                              const float* __restrict__ pooled,
                                              const float* __restrict__ Wf,
                                              const float* __restrict__ bf,
                                              const float* __restrict__ Wtp,
                                              const float* __restrict__ btp,
                                              const float* __restrict__ Wp,
                                              const float* __restrict__ bp,
                                              float* __restrict__ outp,
                                              int B, int SEQ) {
  int g = blockIdx.x;
  int t = threadIdx.x;
  __shared__ float xin[512];
  __shared__ float fs[128];
  for (int i = t; i < SEQ; i += 128) xin[i] = seq[(size_t)g * SEQ + i];
  xin[SEQ + t] = pooled[g * HID + t];
  __syncthreads();
  float acc = bf[t];
#pragma unroll 8
  for (int k = 0; k < 512; ++k) acc = fmaf(xin[k], Wf[(size_t)k * HID + t], acc);
  fs[t] = fmaxf(acc, 0.f);
  __syncthreads();
  if (t == 0) {
    float a0 = btp[0], a1 = btp[1], a2 = bp[0];
    for (int k = 0; k < 128; ++k) {
      float f = fs[k];
      a0 = fmaf(f, Wtp[k * 2 + 0], a0);
      a1 = fmaf(f, Wtp[k * 2 + 1], a1);
      a2 = fmaf(f, Wp[k], a2);
    }
    outp[g * 2 + 0] = a0;
    outp[g * 2 + 1] = a1;
    outp[B * 2 + g] = a2;
  }
}

extern "C" void kernel_launch(void* const* d_in, const int* in_sizes, int n_in,
                              void* d_out, int out_size, void* d_ws, size_t ws_size,
                              hipStream_t stream) {
  const float* seq_emb = (const float*)d_in[0];
  const float* node_x  = (const float*)d_in[1];
  const int*   eidx    = (const int*)d_in[2];
  const int*   nbatch  = (const int*)d_in[3];
  const float* W1  = (const float*)d_in[4];
  const float* b1  = (const float*)d_in[5];
  const float* W2  = (const float*)d_in[6];
  const float* b2  = (const float*)d_in[7];
  const float* Wf  = (const float*)d_in[8];
  const float* bfb = (const float*)d_in[9];
  const float* Wtp = (const float*)d_in[10];
  const float* btp = (const float*)d_in[11];
  const float* Wp  = (const float*)d_in[12];
  const float* bp  = (const float*)d_in[13];

  const int N = in_sizes[3];           // 50000 nodes
  const int E = in_sizes[2] / 2;       // 600000 edges
  const int SEQ = 384;
  const int B = in_sizes[0] / SEQ;     // 64 graphs

  char* w = (char*)d_ws;
  auto alloc = [&](size_t bytes) -> void* {
    void* p = (void*)w;
    w += (bytes + 255) & ~(size_t)255;
    return p;
  };
  float* dinv   = (float*)alloc((size_t)N * 4);
  int*   deg    = (int*)alloc((size_t)N * 4);
  int*   cur    = (int*)alloc((size_t)N * 4);
  int*   offs   = (int*)alloc((size_t)(N + 1) * 4);
  int*   bsum   = (int*)alloc(1024);
  int*   csr    = (int*)alloc((size_t)E * 4);
  float* bufA   = (float*)alloc((size_t)N * HID * 4);
  float* bufB   = (float*)alloc((size_t)N * HID * 4);
  float* pooled = (float*)alloc((size_t)B * HID * 4);

  const int* srcp = eidx;
  const int* dstp = eidx + E;

  hipMemsetAsync(deg, 0, (size_t)N * 4, stream);
  hipMemsetAsync(cur, 0, (size_t)N * 4, stream);

  int gE = (E + 255) / 256;
  int gN = (N + 255) / 256;  // 196 <= 256 (required by scan_bsum_ex)
  hist_k<<<gE, 256, 0, stream>>>(dstp, deg, E);
  dinv_k<<<gN, 256, 0, stream>>>(deg, dinv, N);
  scan_bsum<<<gN, 256, 0, stream>>>(deg, bsum, N);
  scan_bsum_ex<<<1, 256, 0, stream>>>(bsum, gN);
  scan_offsets<<<gN, 256, 0, stream>>>(deg, bsum, offs, N);
  fill_k<<<gE, 256, 0, stream>>>(srcp, dstp, offs, cur, csr, E);

  int gG = (N + 127) / 128;
  int gA = (N + 7) / 8;
  gemm_k<384><<<gG, 256, 0, stream>>>(node_x, W1, dinv, bufA, N);
  agg_k<<<gA, 256, 0, stream>>>((const float4*)bufA, offs, csr, dinv,
                                (const float4*)b1, (float4*)bufB, N);
  gemm_k<128><<<gG, 256, 0, stream>>>(bufB, W2, dinv, bufA, N);
  agg_k<<<gA, 256, 0, stream>>>((const float4*)bufA, offs, csr, dinv,
                                (const float4*)b2, (float4*)bufB, N);
  pool_k<<<B, 256, 0, stream>>>(bufB, nbatch, pooled, N);
  head_k<<<B, 128, 0, stream>>>(seq_emb, pooled, Wf, bfb, Wtp, btp, Wp, bp,
                                (float*)d_out, B, SEQ);
}

// Round 3
// 353.415 us; speedup vs baseline: 1.5405x; 1.1587x over previous
//
#include <hip/hip_runtime.h>

// ---------------------------------------------------------------------------
// 2-layer GCN + mean-pool + MLP head, fp32.
// Pipeline: deg hist -> dinv -> CSR build (scan+fill) -> GEMM1 (scaled) ->
//           AGG1 -> GEMM2 (scaled) -> AGG2 -> POOL(sums) -> HEAD(divide)
// R2: agg_k: 32 lanes/node, float4/lane, edge unroll x4 (latency-bound MLP).
// R3: pool parallelized: 256-node chunks, segmented col-sums + atomicAdd;
//     head_k divides by per-graph count (binary search over sorted batch).
// ---------------------------------------------------------------------------

#define HID 128

__global__ __launch_bounds__(256) void hist_k(const int* __restrict__ dst,
                                              int* __restrict__ cnt, int E) {
  int i = blockIdx.x * 256 + threadIdx.x;
  if (i < E) atomicAdd(&cnt[dst[i]], 1);
}

__global__ __launch_bounds__(256) void dinv_k(const int* __restrict__ cnt,
                                              float* __restrict__ dinv, int N) {
  int i = blockIdx.x * 256 + threadIdx.x;
  if (i < N) dinv[i] = rsqrtf((float)(cnt[i] + 1));  // +1 self-loop
}

// --- 3-kernel exclusive scan over per-node in-degree ---
__global__ __launch_bounds__(256) void scan_bsum(const int* __restrict__ cnt,
                                                 int* __restrict__ bsum, int n) {
  __shared__ int sm[256];
  int i = blockIdx.x * 256 + threadIdx.x;
  int v = (i < n) ? cnt[i] : 0;
  sm[threadIdx.x] = v;
  __syncthreads();
  for (int off = 128; off > 0; off >>= 1) {
    if (threadIdx.x < off) sm[threadIdx.x] += sm[threadIdx.x + off];
    __syncthreads();
  }
  if (threadIdx.x == 0) bsum[blockIdx.x] = sm[0];
}

__global__ __launch_bounds__(256) void scan_bsum_ex(int* bsum, int nb) {
  // single block, nb <= 256
  __shared__ int sm[256];
  int t = threadIdx.x;
  int v = (t < nb) ? bsum[t] : 0;
  sm[t] = v;
  __syncthreads();
  for (int off = 1; off < 256; off <<= 1) {
    int add = (t >= off) ? sm[t - off] : 0;
    __syncthreads();
    sm[t] += add;
    __syncthreads();
  }
  if (t < nb) bsum[t] = sm[t] - v;  // exclusive
}

__global__ __launch_bounds__(256) void scan_offsets(const int* __restrict__ cnt,
                                                    const int* __restrict__ bsum,
                                                    int* __restrict__ offs, int n) {
  __shared__ int sm[256];
  int i = blockIdx.x * 256 + threadIdx.x;
  int t = threadIdx.x;
  int v = (i < n) ? cnt[i] : 0;
  sm[t] = v;
  __syncthreads();
  for (int off = 1; off < 256; off <<= 1) {
    int add = (t >= off) ? sm[t - off] : 0;
    __syncthreads();
    sm[t] += add;
    __syncthreads();
  }
  int base = bsum[blockIdx.x];
  if (i < n) offs[i] = base + sm[t] - v;
  if (i == n - 1) offs[n] = base + sm[t];  // total
}

__global__ __launch_bounds__(256) void fill_k(const int* __restrict__ src,
                                              const int* __restrict__ dst,
                                              const int* __restrict__ offs,
                                              int* __restrict__ cur,
                                              int* __restrict__ csr, int E) {
  int i = blockIdx.x * 256 + threadIdx.x;
  if (i >= E) return;
  int d = dst[i];
  int p = offs[d] + atomicAdd(&cur[d], 1);
  csr[p] = src[i];
}

// --- fp32 GEMM: C[M][128] = (A[M][K] @ W[K][128]) * scale[row] ---
// 128x128 tile, 256 threads, 8x8 acc/thread, K-chunk 32.
template <int K>
__global__ __launch_bounds__(256) void gemm_k(const float* __restrict__ A,
                                              const float* __restrict__ W,
                                              const float* __restrict__ scale,
                                              float* __restrict__ C, int M) {
  __shared__ float As[128][34];  // pad 34: a-reads spread banks, float2-friendly
  __shared__ float Ws[32][HID];
  const int tid = threadIdx.x;
  const int tn = tid & 15;   // 16 col groups: cols tn*4..+3 and 64+tn*4..+3
  const int tm = tid >> 4;   // 16 row groups of 8 rows
  const int row0 = blockIdx.x * 128;

  float acc[8][8];
#pragma unroll
  for (int i = 0; i < 8; ++i)
#pragma unroll
    for (int j = 0; j < 8; ++j) acc[i][j] = 0.f;

  for (int k0 = 0; k0 < K; k0 += 32) {
    // stage W chunk [32][128]: 1024 float4
#pragma unroll
    for (int t = 0; t < 4; ++t) {
      int f = tid + t * 256;
      int kk = f >> 5;
      int cc = (f & 31) << 2;
      *(float4*)&Ws[kk][cc] = *(const float4*)&W[(size_t)(k0 + kk) * HID + cc];
    }
    // stage A chunk [128 rows][32 k]: float4 global read, 4 scalar LDS writes
#pragma unroll
    for (int t = 0; t < 4; ++t) {
      int f = tid + t * 256;
      int rr = f >> 3;
      int kc = (f & 7) << 2;
      int gr = row0 + rr;
      float4 v = make_float4(0.f, 0.f, 0.f, 0.f);
      if (gr < M) v = *(const float4*)&A[(size_t)gr * K + k0 + kc];
      As[rr][kc + 0] = v.x;
      As[rr][kc + 1] = v.y;
      As[rr][kc + 2] = v.z;
      As[rr][kc + 3] = v.w;
    }
    __syncthreads();
#pragma unroll 4
    for (int kk = 0; kk < 32; kk += 2) {
      float2 a2[8];
#pragma unroll
      for (int i = 0; i < 8; ++i) a2[i] = *(const float2*)&As[tm * 8 + i][kk];
      float4 b00 = *(const float4*)&Ws[kk][tn * 4];
      float4 b01 = *(const float4*)&Ws[kk][64 + tn * 4];
      float4 b10 = *(const float4*)&Ws[kk + 1][tn * 4];
      float4 b11 = *(const float4*)&Ws[kk + 1][64 + tn * 4];
      float b0[8] = {b00.x, b00.y, b00.z, b00.w, b01.x, b01.y, b01.z, b01.w};
      float b1[8] = {b10.x, b10.y, b10.z, b10.w, b11.x, b11.y, b11.z, b11.w};
#pragma unroll
      for (int i = 0; i < 8; ++i) {
#pragma unroll
        for (int j = 0; j < 8; ++j) {
          acc[i][j] = fmaf(a2[i].x, b0[j], acc[i][j]);
          acc[i][j] = fmaf(a2[i].y, b1[j], acc[i][j]);
        }
      }
    }
    __syncthreads();
  }
#pragma unroll
  for (int i = 0; i < 8; ++i) {
    int r = row0 + tm * 8 + i;
    if (r < M) {
      float s = scale[r];
      float4 o0, o1;
      o0.x = acc[i][0] * s; o0.y = acc[i][1] * s;
      o0.z = acc[i][2] * s; o0.w = acc[i][3] * s;
      o1.x = acc[i][4] * s; o1.y = acc[i][5] * s;
      o1.z = acc[i][6] * s; o1.w = acc[i][7] * s;
      *(float4*)&C[(size_t)r * HID + tn * 4] = o0;
      *(float4*)&C[(size_t)r * HID + 64 + tn * 4] = o1;
    }
  }
}

// --- aggregation: out[v] = relu(dinv[v]*(sum_{u in in(v)} Hs[u] + Hs[v]) + b)
// Hs pre-scaled by dinv[src]. One node per 32-lane group, float4 per lane,
// edge loop unrolled x4 for memory-level parallelism (latency-bound gather).
__global__ __launch_bounds__(256) void agg_k(const float4* __restrict__ Hs4,
                                             const int* __restrict__ offs,
                                             const int* __restrict__ csr,
                                             const float* __restrict__ dinv,
                                             const float4* __restrict__ bias4,
                                             float4* __restrict__ out4, int N) {
  int grp = threadIdx.x >> 5;          // 8 groups of 32 lanes
  int lane = threadIdx.x & 31;         // lane owns 4 consecutive floats
  int v = blockIdx.x * 8 + grp;
  if (v >= N) return;
  int s = offs[v];
  int e = offs[v + 1];
  float4 acc = Hs4[(size_t)v * 32 + lane];  // self-loop term (pre-scaled)
  int p = s;
  for (; p + 4 <= e; p += 4) {
    int u0 = csr[p + 0];
    int u1 = csr[p + 1];
    int u2 = csr[p + 2];
    int u3 = csr[p + 3];
    float4 x0 = Hs4[(size_t)u0 * 32 + lane];
    float4 x1 = Hs4[(size_t)u1 * 32 + lane];
    float4 x2 = Hs4[(size_t)u2 * 32 + lane];
    float4 x3 = Hs4[(size_t)u3 * 32 + lane];
    acc.x += (x0.x + x1.x) + (x2.x + x3.x);
    acc.y += (x0.y + x1.y) + (x2.y + x3.y);
    acc.z += (x0.z + x1.z) + (x2.z + x3.z);
    acc.w += (x0.w + x1.w) + (x2.w + x3.w);
  }
  for (; p < e; ++p) {
    int u = csr[p];
    float4 x = Hs4[(size_t)u * 32 + lane];
    acc.x += x.x; acc.y += x.y; acc.z += x.z; acc.w += x.w;
  }
  float dv = dinv[v];
  float4 b = bias4[lane];
  float4 o;
  o.x = fmaxf(fmaf(acc.x, dv, b.x), 0.f);
  o.y = fmaxf(fmaf(acc.y, dv, b.y), 0.f);
  o.z = fmaxf(fmaf(acc.z, dv, b.z), 0.f);
  o.w = fmaxf(fmaf(acc.w, dv, b.w), 0.f);
  out4[(size_t)v * 32 + lane] = o;
}

// --- parallel mean-pool stage 1: per-chunk segmented column sums ---
// 256 nodes per block; thread t: col j=t&127, row-half h=t>>7.
// node_batch sorted -> per-thread run-length accumulate, atomicAdd on change.
__global__ __launch_bounds__(256) void pool_sums_k(const float* __restrict__ G,
                                                   const int* __restrict__ batch,
                                                   float* __restrict__ sums, int n) {
  __shared__ int bsm[256];
  int r0 = blockIdx.x * 256;
  int rend = min(r0 + 256, n);
  int cnt = rend - r0;
  int t = threadIdx.x;
  if (t < cnt) bsm[t] = batch[r0 + t];
  __syncthreads();
  int j = t & 127;
  int h = t >> 7;
  if (h >= cnt) return;
  int g_cur = bsm[h];
  float acc = 0.f;
  for (int rr = h; rr < cnt; rr += 2) {
    int g = bsm[rr];
    if (g != g_cur) {
      atomicAdd(&sums[(size_t)g_cur * HID + j], acc);
      acc = 0.f;
      g_cur = g;
    }
    acc += G[(size_t)(r0 + rr) * HID + j];
  }
  atomicAdd(&sums[(size_t)g_cur * HID + j], acc);
}

// --- head: pooled = sums/cnt; fused = relu([seq|pooled] @ Wf + bf);
//     tp = fused@Wtp+btp; pr = fused@Wp+bp
__global__ __launch_bounds__(128) void head_k(const float* __restrict__ seq,
                                              const float* __restrict__ sums,
                                              const int* __restrict__ batch,
                                              const float* __restrict__ Wf,
                                              const float* __restrict__ bf,
                                              const float* __restrict__ Wtp,
                                              const float* __restrict__ btp,
                                              const float* __restrict__ Wp,
                                              const float* __restrict__ bp,
                                              float* __restrict__ outp,
                                              int B, int SEQ, int n) {
  int g = blockIdx.x;
  int t = threadIdx.x;
  __shared__ float xin[512];
  __shared__ float fs[128];
  // per-graph node count via binary search over sorted batch
  int lo = 0, hi = n;
  while (lo < hi) { int mid = (lo + hi) >> 1; if (batch[mid] < g) lo = mid + 1; else hi = mid; }
  int start = lo;
  hi = n;
  while (lo < hi) { int mid = (lo + hi) >> 1; if (batch[mid] <= g) lo = mid + 1; else hi = mid; }
  float inv_cnt = 1.f / fmaxf((float)(lo - start), 1.f);
  for (int i = t; i < SEQ; i += 128) xin[i] = seq[(size_t)g * SEQ + i];
  xin[SEQ + t] = sums[g * HID + t] * inv_cnt;
  __syncthreads();
  float acc = bf[t];
#pragma unroll 8
  for (int k = 0; k < 512; ++k) acc = fmaf(xin[k], Wf[(size_t)k * HID + t], acc);
  fs[t] = fmaxf(acc, 0.f);
  __syncthreads();
  if (t == 0) {
    float a0 = btp[0], a1 = btp[1], a2 = bp[0];
    for (int k = 0; k < 128; ++k) {
      float f = fs[k];
      a0 = fmaf(f, Wtp[k * 2 + 0], a0);
      a1 = fmaf(f, Wtp[k * 2 + 1], a1);
      a2 = fmaf(f, Wp[k], a2);
    }
    outp[g * 2 + 0] = a0;
    outp[g * 2 + 1] = a1;
    outp[B * 2 + g] = a2;
  }
}

extern "C" void kernel_launch(void* const* d_in, const int* in_sizes, int n_in,
                              void* d_out, int out_size, void* d_ws, size_t ws_size,
                              hipStream_t stream) {
  const float* seq_emb = (const float*)d_in[0];
  const float* node_x  = (const float*)d_in[1];
  const int*   eidx    = (const int*)d_in[2];
  const int*   nbatch  = (const int*)d_in[3];
  const float* W1  = (const float*)d_in[4];
  const float* b1  = (const float*)d_in[5];
  const float* W2  = (const float*)d_in[6];
  const float* b2  = (const float*)d_in[7];
  const float* Wf  = (const float*)d_in[8];
  const float* bfb = (const float*)d_in[9];
  const float* Wtp = (const float*)d_in[10];
  const float* btp = (const float*)d_in[11];
  const float* Wp  = (const float*)d_in[12];
  const float* bp  = (const float*)d_in[13];

  const int N = in_sizes[3];           // 50000 nodes
  const int E = in_sizes[2] / 2;       // 600000 edges
  const int SEQ = 384;
  const int B = in_sizes[0] / SEQ;     // 64 graphs

  char* w = (char*)d_ws;
  auto alloc = [&](size_t bytes) -> void* {
    void* p = (void*)w;
    w += (bytes + 255) & ~(size_t)255;
    return p;
  };
  float* dinv   = (float*)alloc((size_t)N * 4);
  int*   deg    = (int*)alloc((size_t)N * 4);
  int*   cur    = (int*)alloc((size_t)N * 4);
  int*   offs   = (int*)alloc((size_t)(N + 1) * 4);
  int*   bsum   = (int*)alloc(1024);
  int*   csr    = (int*)alloc((size_t)E * 4);
  float* bufA   = (float*)alloc((size_t)N * HID * 4);
  float* bufB   = (float*)alloc((size_t)N * HID * 4);
  float* sums   = (float*)alloc((size_t)B * HID * 4);

  const int* srcp = eidx;
  const int* dstp = eidx + E;

  hipMemsetAsync(deg, 0, (size_t)N * 4, stream);
  hipMemsetAsync(cur, 0, (size_t)N * 4, stream);
  hipMemsetAsync(sums, 0, (size_t)B * HID * 4, stream);

  int gE = (E + 255) / 256;
  int gN = (N + 255) / 256;  // 196 <= 256 (required by scan_bsum_ex)
  hist_k<<<gE, 256, 0, stream>>>(dstp, deg, E);
  dinv_k<<<gN, 256, 0, stream>>>(deg, dinv, N);
  scan_bsum<<<gN, 256, 0, stream>>>(deg, bsum, N);
  scan_bsum_ex<<<1, 256, 0, stream>>>(bsum, gN);
  scan_offsets<<<gN, 256, 0, stream>>>(deg, bsum, offs, N);
  fill_k<<<gE, 256, 0, stream>>>(srcp, dstp, offs, cur, csr, E);

  int gG = (N + 127) / 128;
  int gA = (N + 7) / 8;
  gemm_k<384><<<gG, 256, 0, stream>>>(node_x, W1, dinv, bufA, N);
  agg_k<<<gA, 256, 0, stream>>>((const float4*)bufA, offs, csr, dinv,
                                (const float4*)b1, (float4*)bufB, N);
  gemm_k<128><<<gG, 256, 0, stream>>>(bufB, W2, dinv, bufA, N);
  agg_k<<<gA, 256, 0, stream>>>((const float4*)bufA, offs, csr, dinv,
                                (const float4*)b2, (float4*)bufB, N);
  pool_sums_k<<<gN, 256, 0, stream>>>(bufB, nbatch, sums, N);
  head_k<<<B, 128, 0, stream>>>(seq_emb, sums, nbatch, Wf, bfb, Wtp, btp, Wp, bp,
                                (float*)d_out, B, SEQ, N);
}

// Round 4
// 252.434 us; speedup vs baseline: 2.1567x; 1.4000x over previous
//
#include <hip/hip_runtime.h>

// ---------------------------------------------------------------------------
// 2-layer GCN + mean-pool + MLP head.
// R4: GEMMs -> bf16 MFMA (16x16x32), Hs stored bf16 (halves agg gather bytes).
//     A stays fp32 in HBM; converted to bf16 during LDS staging. W pre-
//     transposed/converted to bf16 Wt[c][k] once per call. agg accumulates
//     fp32, outputs fp32. Pool/head/CSR unchanged from R3.
// ---------------------------------------------------------------------------

#define HID 128

typedef __attribute__((ext_vector_type(8))) short bf16x8;
typedef __attribute__((ext_vector_type(4))) short bf16x4;
typedef __attribute__((ext_vector_type(4))) float f32x4;

static __device__ __forceinline__ short f2bf(float f) {
  union { float f; unsigned u; } v; v.f = f;
  unsigned r = v.u + 0x7fff + ((v.u >> 16) & 1);  // RNE
  return (short)(r >> 16);
}
static __device__ __forceinline__ float bf2f(short s) {
  union { unsigned u; float f; } v;
  v.u = ((unsigned)(unsigned short)s) << 16;
  return v.f;
}

__global__ __launch_bounds__(256) void hist_k(const int* __restrict__ dst,
                                              int* __restrict__ cnt, int E) {
  int i = blockIdx.x * 256 + threadIdx.x;
  if (i < E) atomicAdd(&cnt[dst[i]], 1);
}

__global__ __launch_bounds__(256) void dinv_k(const int* __restrict__ cnt,
                                              float* __restrict__ dinv, int N) {
  int i = blockIdx.x * 256 + threadIdx.x;
  if (i < N) dinv[i] = rsqrtf((float)(cnt[i] + 1));  // +1 self-loop
}

// --- 3-kernel exclusive scan over per-node in-degree ---
__global__ __launch_bounds__(256) void scan_bsum(const int* __restrict__ cnt,
                                                 int* __restrict__ bsum, int n) {
  __shared__ int sm[256];
  int i = blockIdx.x * 256 + threadIdx.x;
  int v = (i < n) ? cnt[i] : 0;
  sm[threadIdx.x] = v;
  __syncthreads();
  for (int off = 128; off > 0; off >>= 1) {
    if (threadIdx.x < off) sm[threadIdx.x] += sm[threadIdx.x + off];
    __syncthreads();
  }
  if (threadIdx.x == 0) bsum[blockIdx.x] = sm[0];
}

__global__ __launch_bounds__(256) void scan_bsum_ex(int* bsum, int nb) {
  __shared__ int sm[256];
  int t = threadIdx.x;
  int v = (t < nb) ? bsum[t] : 0;
  sm[t] = v;
  __syncthreads();
  for (int off = 1; off < 256; off <<= 1) {
    int add = (t >= off) ? sm[t - off] : 0;
    __syncthreads();
    sm[t] += add;
    __syncthreads();
  }
  if (t < nb) bsum[t] = sm[t] - v;  // exclusive
}

__global__ __launch_bounds__(256) void scan_offsets(const int* __restrict__ cnt,
                                                    const int* __restrict__ bsum,
                                                    int* __restrict__ offs, int n) {
  __shared__ int sm[256];
  int i = blockIdx.x * 256 + threadIdx.x;
  int t = threadIdx.x;
  int v = (i < n) ? cnt[i] : 0;
  sm[t] = v;
  __syncthreads();
  for (int off = 1; off < 256; off <<= 1) {
    int add = (t >= off) ? sm[t - off] : 0;
    __syncthreads();
    sm[t] += add;
    __syncthreads();
  }
  int base = bsum[blockIdx.x];
  if (i < n) offs[i] = base + sm[t] - v;
  if (i == n - 1) offs[n] = base + sm[t];  // total
}

__global__ __launch_bounds__(256) void fill_k(const int* __restrict__ src,
                                              const int* __restrict__ dst,
                                              const int* __restrict__ offs,
                                              int* __restrict__ cur,
                                              int* __restrict__ csr, int E) {
  int i = blockIdx.x * 256 + threadIdx.x;
  if (i >= E) return;
  int d = dst[i];
  int p = offs[d] + atomicAdd(&cur[d], 1);
  csr[p] = src[i];
}

// --- W[K][128] fp32 -> Wt[128][K] bf16 (transpose + convert) ---
__global__ __launch_bounds__(256) void prep_w_k(const float* __restrict__ W,
                                                short* __restrict__ Wt, int K) {
  int idx = blockIdx.x * 256 + threadIdx.x;
  if (idx >= K * HID) return;
  int k = idx >> 7;
  int c = idx & 127;
  Wt[(size_t)c * K + k] = f2bf(W[idx]);
}

// --- bf16 MFMA GEMM: C[M][128] = bf16( (A[M][K] @ Wt^T) * scale[row] ) ---
// 128x128 tile, 4 waves (2x2 of 64x64), BK=64, mfma_f32_16x16x32_bf16.
// A fp32 in global, converted during staging. Wt is [128 cols][K] bf16.
// LDS rows padded to 72 shorts (144B): lanes 0-15 hit banks 4r%32 -> 2-way.
template <int K>
__global__ __launch_bounds__(256) void mfma_gemm_k(const float* __restrict__ A,
                                                   const short* __restrict__ Wt,
                                                   const float* __restrict__ scale,
                                                   short* __restrict__ C, int M) {
  constexpr int BK = 64;
  constexpr int ROWE = BK + 8;  // padded row length in shorts
  __shared__ short As[128 * ROWE];
  __shared__ short Bs[128 * ROWE];
  __shared__ float dln[128];

  const int tid = threadIdx.x;
  const int wave = tid >> 6;
  const int lane = tid & 63;
  const int l15 = lane & 15;
  const int lk = lane >> 4;          // k-group 0..3
  const int mh = (wave >> 1) * 64;   // wave row offset in tile
  const int nh = (wave & 1) * 64;    // wave col offset
  const int row0 = blockIdx.x * 128;

  if (tid < 128) {
    int r = row0 + tid;
    dln[tid] = (r < M) ? scale[r] : 0.f;
  }

  f32x4 acc[4][4] = {};

  for (int k0 = 0; k0 < K; k0 += BK) {
    __syncthreads();  // previous iter's LDS reads done before overwrite
    // stage A [128][64] fp32 -> bf16 (float4 per thread x8)
#pragma unroll
    for (int it = 0; it < 8; ++it) {
      int f = tid + it * 256;          // 0..2047
      int r = f >> 4;                  // 16 float4 per row
      int kc = (f & 15) << 2;
      int gr = row0 + r;
      float4 v = make_float4(0.f, 0.f, 0.f, 0.f);
      if (gr < M) v = *(const float4*)&A[(size_t)gr * K + k0 + kc];
      short* d = &As[r * ROWE + kc];
      d[0] = f2bf(v.x); d[1] = f2bf(v.y); d[2] = f2bf(v.z); d[3] = f2bf(v.w);
    }
    // stage Wt [128][64] bf16 (bf16x8 per thread x4)
#pragma unroll
    for (int it = 0; it < 4; ++it) {
      int f = tid + it * 256;          // 0..1023
      int r = f >> 3;
      int kc = (f & 7) << 3;
      *(bf16x8*)&Bs[r * ROWE + kc] =
          *(const bf16x8*)&Wt[(size_t)r * K + k0 + kc];
    }
    __syncthreads();
    // compute: 2 k-sub-steps of 32, 4x4 fragments of 16x16
#pragma unroll
    for (int ks = 0; ks < 2; ++ks) {
      bf16x8 af[4], bfr[4];
#pragma unroll
      for (int mf = 0; mf < 4; ++mf)
        af[mf] = *(const bf16x8*)&As[(mh + mf * 16 + l15) * ROWE + ks * 32 + lk * 8];
#pragma unroll
      for (int nf = 0; nf < 4; ++nf)
        bfr[nf] = *(const bf16x8*)&Bs[(nh + nf * 16 + l15) * ROWE + ks * 32 + lk * 8];
#pragma unroll
      for (int mf = 0; mf < 4; ++mf)
#pragma unroll
        for (int nf = 0; nf < 4; ++nf)
          acc[mf][nf] = __builtin_amdgcn_mfma_f32_16x16x32_bf16(
              af[mf], bfr[nf], acc[mf][nf], 0, 0, 0);
    }
  }
  // epilogue: C[row][col] bf16, row = mh+mf*16+lk*4+r, col = nh+nf*16+l15
#pragma unroll
  for (int mf = 0; mf < 4; ++mf) {
#pragma unroll
    for (int r = 0; r < 4; ++r) {
      int lr = mh + mf * 16 + lk * 4 + r;
      int gr = row0 + lr;
      if (gr >= M) continue;
      float s = dln[lr];
#pragma unroll
      for (int nf = 0; nf < 4; ++nf)
        C[(size_t)gr * HID + nh + nf * 16 + l15] = f2bf(acc[mf][nf][r] * s);
    }
  }
}

// --- aggregation: out[v] = relu(dinv[v]*(sum_in Hs[u] + Hs[v]) + b), Hs bf16.
// 32 lanes/node (bf16x4 = 8B per lane), edge unroll x4 for MLP.
__global__ __launch_bounds__(256) void agg_k(const short* __restrict__ Hs,
                                             const int* __restrict__ offs,
                                             const int* __restrict__ csr,
                                             const float* __restrict__ dinv,
                                             const float* __restrict__ bias,
                                             float* __restrict__ out, int N) {
  int grp = threadIdx.x >> 5;
  int lane = threadIdx.x & 31;
  int v = blockIdx.x * 8 + grp;
  if (v >= N) return;
  int s = offs[v];
  int e = offs[v + 1];
  int c0 = lane << 2;
  bf16x4 sv = *(const bf16x4*)&Hs[(size_t)v * HID + c0];
  float ax = bf2f(sv[0]), ay = bf2f(sv[1]), az = bf2f(sv[2]), aw = bf2f(sv[3]);
  int p = s;
  for (; p + 4 <= e; p += 4) {
    int u0 = csr[p + 0];
    int u1 = csr[p + 1];
    int u2 = csr[p + 2];
    int u3 = csr[p + 3];
    bf16x4 x0 = *(const bf16x4*)&Hs[(size_t)u0 * HID + c0];
    bf16x4 x1 = *(const bf16x4*)&Hs[(size_t)u1 * HID + c0];
    bf16x4 x2 = *(const bf16x4*)&Hs[(size_t)u2 * HID + c0];
    bf16x4 x3 = *(const bf16x4*)&Hs[(size_t)u3 * HID + c0];
    ax += (bf2f(x0[0]) + bf2f(x1[0])) + (bf2f(x2[0]) + bf2f(x3[0]));
    ay += (bf2f(x0[1]) + bf2f(x1[1])) + (bf2f(x2[1]) + bf2f(x3[1]));
    az += (bf2f(x0[2]) + bf2f(x1[2])) + (bf2f(x2[2]) + bf2f(x3[2]));
    aw += (bf2f(x0[3]) + bf2f(x1[3])) + (bf2f(x2[3]) + bf2f(x3[3]));
  }
  for (; p < e; ++p) {
    int u = csr[p];
    bf16x4 x = *(const bf16x4*)&Hs[(size_t)u * HID + c0];
    ax += bf2f(x[0]); ay += bf2f(x[1]); az += bf2f(x[2]); aw += bf2f(x[3]);
  }
  float dv = dinv[v];
  float4 b = *(const float4*)&bias[c0];
  float4 o;
  o.x = fmaxf(fmaf(ax, dv, b.x), 0.f);
  o.y = fmaxf(fmaf(ay, dv, b.y), 0.f);
  o.z = fmaxf(fmaf(az, dv, b.z), 0.f);
  o.w = fmaxf(fmaf(aw, dv, b.w), 0.f);
  *(float4*)&out[(size_t)v * HID + c0] = o;
}

// --- parallel mean-pool stage 1: per-chunk segmented column sums ---
__global__ __launch_bounds__(256) void pool_sums_k(const float* __restrict__ G,
                                                   const int* __restrict__ batch,
                                                   float* __restrict__ sums, int n) {
  __shared__ int bsm[256];
  int r0 = blockIdx.x * 256;
  int rend = min(r0 + 256, n);
  int cnt = rend - r0;
  int t = threadIdx.x;
  if (t < cnt) bsm[t] = batch[r0 + t];
  __syncthreads();
  int j = t & 127;
  int h = t >> 7;
  if (h >= cnt) return;
  int g_cur = bsm[h];
  float acc = 0.f;
  for (int rr = h; rr < cnt; rr += 2) {
    int g = bsm[rr];
    if (g != g_cur) {
      atomicAdd(&sums[(size_t)g_cur * HID + j], acc);
      acc = 0.f;
      g_cur = g;
    }
    acc += G[(size_t)(r0 + rr) * HID + j];
  }
  atomicAdd(&sums[(size_t)g_cur * HID + j], acc);
}

// --- head: pooled = sums/cnt; fused = relu([seq|pooled] @ Wf + bf); outputs ---
__global__ __launch_bounds__(128) void head_k(const float* __restrict__ seq,
                                              const float* __restrict__ sums,
                                              const int* __restrict__ batch,
                                              const float* __restrict__ Wf,
                                              const float* __restrict__ bf,
                                              const float* __restrict__ Wtp,
                                              const float* __restrict__ btp,
                                              const float* __restrict__ Wp,
                                              const float* __restrict__ bp,
                                              float* __restrict__ outp,
                                              int B, int SEQ, int n) {
  int g = blockIdx.x;
  int t = threadIdx.x;
  __shared__ float xin[512];
  __shared__ float fs[128];
  int lo = 0, hi = n;
  while (lo < hi) { int mid = (lo + hi) >> 1; if (batch[mid] < g) lo = mid + 1; else hi = mid; }
  int start = lo;
  hi = n;
  while (lo < hi) { int mid = (lo + hi) >> 1; if (batch[mid] <= g) lo = mid + 1; else hi = mid; }
  float inv_cnt = 1.f / fmaxf((float)(lo - start), 1.f);
  for (int i = t; i < SEQ; i += 128) xin[i] = seq[(size_t)g * SEQ + i];
  xin[SEQ + t] = sums[g * HID + t] * inv_cnt;
  __syncthreads();
  float acc = bf[t];
#pragma unroll 8
  for (int k = 0; k < 512; ++k) acc = fmaf(xin[k], Wf[(size_t)k * HID + t], acc);
  fs[t] = fmaxf(acc, 0.f);
  __syncthreads();
  if (t == 0) {
    float a0 = btp[0], a1 = btp[1], a2 = bp[0];
    for (int k = 0; k < 128; ++k) {
      float f = fs[k];
      a0 = fmaf(f, Wtp[k * 2 + 0], a0);
      a1 = fmaf(f, Wtp[k * 2 + 1], a1);
      a2 = fmaf(f, Wp[k], a2);
    }
    outp[g * 2 + 0] = a0;
    outp[g * 2 + 1] = a1;
    outp[B * 2 + g] = a2;
  }
}

extern "C" void kernel_launch(void* const* d_in, const int* in_sizes, int n_in,
                              void* d_out, int out_size, void* d_ws, size_t ws_size,
                              hipStream_t stream) {
  const float* seq_emb = (const float*)d_in[0];
  const float* node_x  = (const float*)d_in[1];
  const int*   eidx    = (const int*)d_in[2];
  const int*   nbatch  = (const int*)d_in[3];
  const float* W1  = (const float*)d_in[4];
  const float* b1  = (const float*)d_in[5];
  const float* W2  = (const float*)d_in[6];
  const float* b2  = (const float*)d_in[7];
  const float* Wf  = (const float*)d_in[8];
  const float* bfb = (const float*)d_in[9];
  const float* Wtp = (const float*)d_in[10];
  const float* btp = (const float*)d_in[11];
  const float* Wp  = (const float*)d_in[12];
  const float* bp  = (const float*)d_in[13];

  const int N = in_sizes[3];           // 50000 nodes
  const int E = in_sizes[2] / 2;       // 600000 edges
  const int SEQ = 384;
  const int B = in_sizes[0] / SEQ;     // 64 graphs

  char* w = (char*)d_ws;
  auto alloc = [&](size_t bytes) -> void* {
    void* p = (void*)w;
    w += (bytes + 255) & ~(size_t)255;
    return p;
  };
  float* dinv   = (float*)alloc((size_t)N * 4);
  int*   deg    = (int*)alloc((size_t)N * 4);
  int*   cur    = (int*)alloc((size_t)N * 4);
  int*   offs   = (int*)alloc((size_t)(N + 1) * 4);
  int*   bsum   = (int*)alloc(1024);
  int*   csr    = (int*)alloc((size_t)E * 4);
  short* W1t    = (short*)alloc((size_t)SEQ * HID * 2);
  short* W2t    = (short*)alloc((size_t)HID * HID * 2);
  short* bufC   = (short*)alloc((size_t)N * HID * 2);   // Hs bf16
  float* bufG   = (float*)alloc((size_t)N * HID * 4);   // g fp32
  float* sums   = (float*)alloc((size_t)B * HID * 4);

  const int* srcp = eidx;
  const int* dstp = eidx + E;

  hipMemsetAsync(deg, 0, (size_t)N * 4, stream);
  hipMemsetAsync(cur, 0, (size_t)N * 4, stream);
  hipMemsetAsync(sums, 0, (size_t)B * HID * 4, stream);

  int gE = (E + 255) / 256;
  int gN = (N + 255) / 256;  // 196 <= 256 (required by scan_bsum_ex)
  hist_k<<<gE, 256, 0, stream>>>(dstp, deg, E);
  dinv_k<<<gN, 256, 0, stream>>>(deg, dinv, N);
  scan_bsum<<<gN, 256, 0, stream>>>(deg, bsum, N);
  scan_bsum_ex<<<1, 256, 0, stream>>>(bsum, gN);
  scan_offsets<<<gN, 256, 0, stream>>>(deg, bsum, offs, N);
  fill_k<<<gE, 256, 0, stream>>>(srcp, dstp, offs, cur, csr, E);

  prep_w_k<<<(SEQ * HID + 255) / 256, 256, 0, stream>>>(W1, W1t, SEQ);
  prep_w_k<<<(HID * HID + 255) / 256, 256, 0, stream>>>(W2, W2t, HID);

  int gG = (N + 127) / 128;
  int gA = (N + 7) / 8;
  mfma_gemm_k<384><<<gG, 256, 0, stream>>>(node_x, W1t, dinv, bufC, N);
  agg_k<<<gA, 256, 0, stream>>>(bufC, offs, csr, dinv, b1, bufG, N);
  mfma_gemm_k<128><<<gG, 256, 0, stream>>>(bufG, W2t, dinv, bufC, N);
  agg_k<<<gA, 256, 0, stream>>>(bufC, offs, csr, dinv, b2, bufG, N);
  pool_sums_k<<<gN, 256, 0, stream>>>(bufG, nbatch, sums, N);
  head_k<<<B, 128, 0, stream>>>(seq_emb, sums, nbatch, Wf, bfb, Wtp, btp, Wp, bp,
                                (float*)d_out, B, SEQ, N);
}

// Round 5
// 243.951 us; speedup vs baseline: 2.2317x; 1.0348x over previous
//
#include <hip/hip_runtime.h>

// ---------------------------------------------------------------------------
// 2-layer GCN + mean-pool + MLP head.
// R4: bf16 MFMA GEMMs, Hs bf16.
// R5: GEMM tile 64x128 (3+ blocks/CU, was 1.5 -> latency-bound), packed
//     bf16x4 LDS writes in staging, agg outputs bf16 (bit-identical for
//     layer-2 input; pool reads bf16), GEMM2 stages bf16 directly.
// ---------------------------------------------------------------------------

#define HID 128

typedef __attribute__((ext_vector_type(8))) short bf16x8;
typedef __attribute__((ext_vector_type(4))) short bf16x4;
typedef __attribute__((ext_vector_type(4))) float f32x4;

static __device__ __forceinline__ short f2bf(float f) {
  union { float f; unsigned u; } v; v.f = f;
  unsigned r = v.u + 0x7fff + ((v.u >> 16) & 1);  // RNE
  return (short)(r >> 16);
}
static __device__ __forceinline__ float bf2f(short s) {
  union { unsigned u; float f; } v;
  v.u = ((unsigned)(unsigned short)s) << 16;
  return v.f;
}

__global__ __launch_bounds__(256) void hist_k(const int* __restrict__ dst,
                                              int* __restrict__ cnt, int E) {
  int i = blockIdx.x * 256 + threadIdx.x;
  if (i < E) atomicAdd(&cnt[dst[i]], 1);
}

__global__ __launch_bounds__(256) void dinv_k(const int* __restrict__ cnt,
                                              float* __restrict__ dinv, int N) {
  int i = blockIdx.x * 256 + threadIdx.x;
  if (i < N) dinv[i] = rsqrtf((float)(cnt[i] + 1));  // +1 self-loop
}

// --- 3-kernel exclusive scan over per-node in-degree ---
__global__ __launch_bounds__(256) void scan_bsum(const int* __restrict__ cnt,
                                                 int* __restrict__ bsum, int n) {
  __shared__ int sm[256];
  int i = blockIdx.x * 256 + threadIdx.x;
  int v = (i < n) ? cnt[i] : 0;
  sm[threadIdx.x] = v;
  __syncthreads();
  for (int off = 128; off > 0; off >>= 1) {
    if (threadIdx.x < off) sm[threadIdx.x] += sm[threadIdx.x + off];
    __syncthreads();
  }
  if (threadIdx.x == 0) bsum[blockIdx.x] = sm[0];
}

__global__ __launch_bounds__(256) void scan_bsum_ex(int* bsum, int nb) {
  __shared__ int sm[256];
  int t = threadIdx.x;
  int v = (t < nb) ? bsum[t] : 0;
  sm[t] = v;
  __syncthreads();
  for (int off = 1; off < 256; off <<= 1) {
    int add = (t >= off) ? sm[t - off] : 0;
    __syncthreads();
    sm[t] += add;
    __syncthreads();
  }
  if (t < nb) bsum[t] = sm[t] - v;  // exclusive
}

__global__ __launch_bounds__(256) void scan_offsets(const int* __restrict__ cnt,
                                                    const int* __restrict__ bsum,
                                                    int* __restrict__ offs, int n) {
  __shared__ int sm[256];
  int i = blockIdx.x * 256 + threadIdx.x;
  int t = threadIdx.x;
  int v = (i < n) ? cnt[i] : 0;
  sm[t] = v;
  __syncthreads();
  for (int off = 1; off < 256; off <<= 1) {
    int add = (t >= off) ? sm[t - off] : 0;
    __syncthreads();
    sm[t] += add;
    __syncthreads();
  }
  int base = bsum[blockIdx.x];
  if (i < n) offs[i] = base + sm[t] - v;
  if (i == n - 1) offs[n] = base + sm[t];  // total
}

__global__ __launch_bounds__(256) void fill_k(const int* __restrict__ src,
                                              const int* __restrict__ dst,
                                              const int* __restrict__ offs,
                                              int* __restrict__ cur,
                                              int* __restrict__ csr, int E) {
  int i = blockIdx.x * 256 + threadIdx.x;
  if (i >= E) return;
  int d = dst[i];
  int p = offs[d] + atomicAdd(&cur[d], 1);
  csr[p] = src[i];
}

// --- W[K][128] fp32 -> Wt[128][K] bf16 (transpose + convert) ---
__global__ __launch_bounds__(256) void prep_w_k(const float* __restrict__ W,
                                                short* __restrict__ Wt, int K) {
  int idx = blockIdx.x * 256 + threadIdx.x;
  if (idx >= K * HID) return;
  int k = idx >> 7;
  int c = idx & 127;
  Wt[(size_t)c * K + k] = f2bf(W[idx]);
}

// --- bf16 MFMA GEMM: C[M][128] = bf16( (A[M][K] @ Wt^T) * scale[row] ) ---
// 64x128 tile, 4 waves (2x2 of 32x64), BK=64, mfma_f32_16x16x32_bf16.
// BF16SRC: A is bf16 [M][K] (vector-copy staging); else fp32 (convert+pack).
template <int K, bool BF16SRC>
__global__ __launch_bounds__(256) void mfma_gemm_k(const void* __restrict__ Av,
                                                   const short* __restrict__ Wt,
                                                   const float* __restrict__ scale,
                                                   short* __restrict__ C, int M) {
  constexpr int BK = 64;
  constexpr int ROWE = BK + 8;  // 72 shorts = 144B rows (16B aligned)
  __shared__ short As[64 * ROWE];
  __shared__ short Bs[128 * ROWE];
  __shared__ float dln[64];

  const int tid = threadIdx.x;
  const int wave = tid >> 6;
  const int lane = tid & 63;
  const int l15 = lane & 15;
  const int lk = lane >> 4;          // k-group 0..3
  const int mh = (wave >> 1) * 32;   // wave row offset in tile
  const int nh = (wave & 1) * 64;    // wave col offset
  const int row0 = blockIdx.x * 64;

  if (tid < 64) {
    int r = row0 + tid;
    dln[tid] = (r < M) ? scale[r] : 0.f;
  }

  f32x4 acc[2][4] = {};

  for (int k0 = 0; k0 < K; k0 += BK) {
    __syncthreads();  // previous iter's LDS reads done before overwrite
    if (BF16SRC) {
      const short* Ab = (const short*)Av;
      // stage A [64][64] bf16: 512 bf16x8 -> 2 per thread
#pragma unroll
      for (int it = 0; it < 2; ++it) {
        int f = tid + it * 256;
        int r = f >> 3;
        int kc = (f & 7) << 3;
        int gr = row0 + r;
        bf16x8 v = {};
        if (gr < M) v = *(const bf16x8*)&Ab[(size_t)gr * K + k0 + kc];
        *(bf16x8*)&As[r * ROWE + kc] = v;
      }
    } else {
      const float* Af = (const float*)Av;
      // stage A [64][64] fp32 -> bf16: 1024 float4 -> 4 per thread, 8B writes
#pragma unroll
      for (int it = 0; it < 4; ++it) {
        int f = tid + it * 256;
        int r = f >> 4;
        int kc = (f & 15) << 2;
        int gr = row0 + r;
        float4 v = make_float4(0.f, 0.f, 0.f, 0.f);
        if (gr < M) v = *(const float4*)&Af[(size_t)gr * K + k0 + kc];
        bf16x4 s;
        s[0] = f2bf(v.x); s[1] = f2bf(v.y); s[2] = f2bf(v.z); s[3] = f2bf(v.w);
        *(bf16x4*)&As[r * ROWE + kc] = s;
      }
    }
    // stage Wt [128][64] bf16: 1024 bf16x8 -> 4 per thread
#pragma unroll
    for (int it = 0; it < 4; ++it) {
      int f = tid + it * 256;
      int r = f >> 3;
      int kc = (f & 7) << 3;
      *(bf16x8*)&Bs[r * ROWE + kc] =
          *(const bf16x8*)&Wt[(size_t)r * K + k0 + kc];
    }
    __syncthreads();
    // compute: 2 k-sub-steps of 32, 2x4 fragments of 16x16
#pragma unroll
    for (int ks = 0; ks < 2; ++ks) {
      bf16x8 af[2], bfr[4];
#pragma unroll
      for (int mf = 0; mf < 2; ++mf)
        af[mf] = *(const bf16x8*)&As[(mh + mf * 16 + l15) * ROWE + ks * 32 + lk * 8];
#pragma unroll
      for (int nf = 0; nf < 4; ++nf)
        bfr[nf] = *(const bf16x8*)&Bs[(nh + nf * 16 + l15) * ROWE + ks * 32 + lk * 8];
#pragma unroll
      for (int mf = 0; mf < 2; ++mf)
#pragma unroll
        for (int nf = 0; nf < 4; ++nf)
          acc[mf][nf] = __builtin_amdgcn_mfma_f32_16x16x32_bf16(
              af[mf], bfr[nf], acc[mf][nf], 0, 0, 0);
    }
  }
  // epilogue: C/D layout col=lane&15, row=(lane>>4)*4+reg
#pragma unroll
  for (int mf = 0; mf < 2; ++mf) {
#pragma unroll
    for (int r = 0; r < 4; ++r) {
      int lr = mh + mf * 16 + lk * 4 + r;
      int gr = row0 + lr;
      if (gr >= M) continue;
      float s = dln[lr];
#pragma unroll
      for (int nf = 0; nf < 4; ++nf)
        C[(size_t)gr * HID + nh + nf * 16 + l15] = f2bf(acc[mf][nf][r] * s);
    }
  }
}

// --- aggregation: out[v] = bf16(relu(dinv[v]*(sum_in Hs[u] + Hs[v]) + b))
// Hs bf16. 32 lanes/node (8B per lane), edge unroll x4 for MLP.
__global__ __launch_bounds__(256) void agg_k(const short* __restrict__ Hs,
                                             const int* __restrict__ offs,
                                             const int* __restrict__ csr,
                                             const float* __restrict__ dinv,
                                             const float* __restrict__ bias,
                                             short* __restrict__ out, int N) {
  int grp = threadIdx.x >> 5;
  int lane = threadIdx.x & 31;
  int v = blockIdx.x * 8 + grp;
  if (v >= N) return;
  int s = offs[v];
  int e = offs[v + 1];
  int c0 = lane << 2;
  bf16x4 sv = *(const bf16x4*)&Hs[(size_t)v * HID + c0];
  float ax = bf2f(sv[0]), ay = bf2f(sv[1]), az = bf2f(sv[2]), aw = bf2f(sv[3]);
  int p = s;
  for (; p + 4 <= e; p += 4) {
    int u0 = csr[p + 0];
    int u1 = csr[p + 1];
    int u2 = csr[p + 2];
    int u3 = csr[p + 3];
    bf16x4 x0 = *(const bf16x4*)&Hs[(size_t)u0 * HID + c0];
    bf16x4 x1 = *(const bf16x4*)&Hs[(size_t)u1 * HID + c0];
    bf16x4 x2 = *(const bf16x4*)&Hs[(size_t)u2 * HID + c0];
    bf16x4 x3 = *(const bf16x4*)&Hs[(size_t)u3 * HID + c0];
    ax += (bf2f(x0[0]) + bf2f(x1[0])) + (bf2f(x2[0]) + bf2f(x3[0]));
    ay += (bf2f(x0[1]) + bf2f(x1[1])) + (bf2f(x2[1]) + bf2f(x3[1]));
    az += (bf2f(x0[2]) + bf2f(x1[2])) + (bf2f(x2[2]) + bf2f(x3[2]));
    aw += (bf2f(x0[3]) + bf2f(x1[3])) + (bf2f(x2[3]) + bf2f(x3[3]));
  }
  for (; p < e; ++p) {
    int u = csr[p];
    bf16x4 x = *(const bf16x4*)&Hs[(size_t)u * HID + c0];
    ax += bf2f(x[0]); ay += bf2f(x[1]); az += bf2f(x[2]); aw += bf2f(x[3]);
  }
  float dv = dinv[v];
  float4 b = *(const float4*)&bias[c0];
  bf16x4 o;
  o[0] = f2bf(fmaxf(fmaf(ax, dv, b.x), 0.f));
  o[1] = f2bf(fmaxf(fmaf(ay, dv, b.y), 0.f));
  o[2] = f2bf(fmaxf(fmaf(az, dv, b.z), 0.f));
  o[3] = f2bf(fmaxf(fmaf(aw, dv, b.w), 0.f));
  *(bf16x4*)&out[(size_t)v * HID + c0] = o;
}

// --- parallel mean-pool stage 1: per-chunk segmented column sums (bf16 in) ---
__global__ __launch_bounds__(256) void pool_sums_k(const short* __restrict__ G,
                                                   const int* __restrict__ batch,
                                                   float* __restrict__ sums, int n) {
  __shared__ int bsm[256];
  int r0 = blockIdx.x * 256;
  int rend = min(r0 + 256, n);
  int cnt = rend - r0;
  int t = threadIdx.x;
  if (t < cnt) bsm[t] = batch[r0 + t];
  __syncthreads();
  int j = t & 127;
  int h = t >> 7;
  if (h >= cnt) return;
  int g_cur = bsm[h];
  float acc = 0.f;
  for (int rr = h; rr < cnt; rr += 2) {
    int g = bsm[rr];
    if (g != g_cur) {
      atomicAdd(&sums[(size_t)g_cur * HID + j], acc);
      acc = 0.f;
      g_cur = g;
    }
    acc += bf2f(G[(size_t)(r0 + rr) * HID + j]);
  }
  atomicAdd(&sums[(size_t)g_cur * HID + j], acc);
}

// --- head: pooled = sums/cnt; fused = relu([seq|pooled] @ Wf + bf); outputs ---
__global__ __launch_bounds__(128) void head_k(const float* __restrict__ seq,
                                              const float* __restrict__ sums,
                                              const int* __restrict__ batch,
                                              const float* __restrict__ Wf,
                                              const float* __restrict__ bf,
                                              const float* __restrict__ Wtp,
                                              const float* __restrict__ btp,
                                              const float* __restrict__ Wp,
                                              const float* __restrict__ bp,
                                              float* __restrict__ outp,
                                              int B, int SEQ, int n) {
  int g = blockIdx.x;
  int t = threadIdx.x;
  __shared__ float xin[512];
  __shared__ float fs[128];
  int lo = 0, hi = n;
  while (lo < hi) { int mid = (lo + hi) >> 1; if (batch[mid] < g) lo = mid + 1; else hi = mid; }
  int start = lo;
  hi = n;
  while (lo < hi) { int mid = (lo + hi) >> 1; if (batch[mid] <= g) lo = mid + 1; else hi = mid; }
  float inv_cnt = 1.f / fmaxf((float)(lo - start), 1.f);
  for (int i = t; i < SEQ; i += 128) xin[i] = seq[(size_t)g * SEQ + i];
  xin[SEQ + t] = sums[g * HID + t] * inv_cnt;
  __syncthreads();
  float acc = bf[t];
#pragma unroll 8
  for (int k = 0; k < 512; ++k) acc = fmaf(xin[k], Wf[(size_t)k * HID + t], acc);
  fs[t] = fmaxf(acc, 0.f);
  __syncthreads();
  if (t == 0) {
    float a0 = btp[0], a1 = btp[1], a2 = bp[0];
    for (int k = 0; k < 128; ++k) {
      float f = fs[k];
      a0 = fmaf(f, Wtp[k * 2 + 0], a0);
      a1 = fmaf(f, Wtp[k * 2 + 1], a1);
      a2 = fmaf(f, Wp[k], a2);
    }
    outp[g * 2 + 0] = a0;
    outp[g * 2 + 1] = a1;
    outp[B * 2 + g] = a2;
  }
}

extern "C" void kernel_launch(void* const* d_in, const int* in_sizes, int n_in,
                              void* d_out, int out_size, void* d_ws, size_t ws_size,
                              hipStream_t stream) {
  const float* seq_emb = (const float*)d_in[0];
  const float* node_x  = (const float*)d_in[1];
  const int*   eidx    = (const int*)d_in[2];
  const int*   nbatch  = (const int*)d_in[3];
  const float* W1  = (const float*)d_in[4];
  const float* b1  = (const float*)d_in[5];
  const float* W2  = (const float*)d_in[6];
  const float* b2  = (const float*)d_in[7];
  const float* Wf  = (const float*)d_in[8];
  const float* bfb = (const float*)d_in[9];
  const float* Wtp = (const float*)d_in[10];
  const float* btp = (const float*)d_in[11];
  const float* Wp  = (const float*)d_in[12];
  const float* bp  = (const float*)d_in[13];

  const int N = in_sizes[3];           // 50000 nodes
  const int E = in_sizes[2] / 2;       // 600000 edges
  const int SEQ = 384;
  const int B = in_sizes[0] / SEQ;     // 64 graphs

  char* w = (char*)d_ws;
  auto alloc = [&](size_t bytes) -> void* {
    void* p = (void*)w;
    w += (bytes + 255) & ~(size_t)255;
    return p;
  };
  float* dinv   = (float*)alloc((size_t)N * 4);
  int*   deg    = (int*)alloc((size_t)N * 4);
  int*   cur    = (int*)alloc((size_t)N * 4);
  int*   offs   = (int*)alloc((size_t)(N + 1) * 4);
  int*   bsum   = (int*)alloc(1024);
  int*   csr    = (int*)alloc((size_t)E * 4);
  short* W1t    = (short*)alloc((size_t)SEQ * HID * 2);
  short* W2t    = (short*)alloc((size_t)HID * HID * 2);
  short* bufC   = (short*)alloc((size_t)N * HID * 2);   // Hs bf16
  short* bufG   = (short*)alloc((size_t)N * HID * 2);   // g bf16
  float* sums   = (float*)alloc((size_t)B * HID * 4);

  const int* srcp = eidx;
  const int* dstp = eidx + E;

  hipMemsetAsync(deg, 0, (size_t)N * 4, stream);
  hipMemsetAsync(cur, 0, (size_t)N * 4, stream);
  hipMemsetAsync(sums, 0, (size_t)B * HID * 4, stream);

  int gE = (E + 255) / 256;
  int gN = (N + 255) / 256;  // 196 <= 256 (required by scan_bsum_ex)
  hist_k<<<gE, 256, 0, stream>>>(dstp, deg, E);
  dinv_k<<<gN, 256, 0, stream>>>(deg, dinv, N);
  scan_bsum<<<gN, 256, 0, stream>>>(deg, bsum, N);
  scan_bsum_ex<<<1, 256, 0, stream>>>(bsum, gN);
  scan_offsets<<<gN, 256, 0, stream>>>(deg, bsum, offs, N);
  fill_k<<<gE, 256, 0, stream>>>(srcp, dstp, offs, cur, csr, E);

  prep_w_k<<<(SEQ * HID + 255) / 256, 256, 0, stream>>>(W1, W1t, SEQ);
  prep_w_k<<<(HID * HID + 255) / 256, 256, 0, stream>>>(W2, W2t, HID);

  int gG = (N + 63) / 64;
  int gA = (N + 7) / 8;
  mfma_gemm_k<384, false><<<gG, 256, 0, stream>>>(node_x, W1t, dinv, bufC, N);
  agg_k<<<gA, 256, 0, stream>>>(bufC, offs, csr, dinv, b1, bufG, N);
  mfma_gemm_k<128, true><<<gG, 256, 0, stream>>>(bufG, W2t, dinv, bufC, N);
  agg_k<<<gA, 256, 0, stream>>>(bufC, offs, csr, dinv, b2, bufG, N);
  pool_sums_k<<<gN, 256, 0, stream>>>(bufG, nbatch, sums, N);
  head_k<<<B, 128, 0, stream>>>(seq_emb, sums, nbatch, Wf, bfb, Wtp, btp, Wp, bp,
                                (float*)d_out, B, SEQ, N);
}

// Round 6
// 230.988 us; speedup vs baseline: 2.3570x; 1.0561x over previous
//
#include <hip/hip_runtime.h>

// ---------------------------------------------------------------------------
// 2-layer GCN + mean-pool + MLP head.
// R4: bf16 MFMA GEMMs, Hs bf16. R5: 64x128 GEMM tile, agg/pool bf16.
// R6: agg 16 lanes/node x bf16x8 (2x in-flight bytes/lane);
//     kernel-count diet: dinv folded into scan_bsum, bsum-scan inlined into
//     scan_offsets (+cur=0), single prep_w launch. 13 dispatches total.
// ---------------------------------------------------------------------------

#define HID 128

typedef __attribute__((ext_vector_type(8))) short bf16x8;
typedef __attribute__((ext_vector_type(4))) short bf16x4;
typedef __attribute__((ext_vector_type(4))) float f32x4;

static __device__ __forceinline__ short f2bf(float f) {
  union { float f; unsigned u; } v; v.f = f;
  unsigned r = v.u + 0x7fff + ((v.u >> 16) & 1);  // RNE
  return (short)(r >> 16);
}
static __device__ __forceinline__ float bf2f(short s) {
  union { unsigned u; float f; } v;
  v.u = ((unsigned)(unsigned short)s) << 16;
  return v.f;
}

__global__ __launch_bounds__(256) void hist_k(const int* __restrict__ dst,
                                              int* __restrict__ cnt, int E) {
  int i = blockIdx.x * 256 + threadIdx.x;
  if (i < E) atomicAdd(&cnt[dst[i]], 1);
}

// per-256-chunk sums of deg + dinv computation (fused)
__global__ __launch_bounds__(256) void scan_bsum(const int* __restrict__ cnt,
                                                 int* __restrict__ bsum,
                                                 float* __restrict__ dinv, int n) {
  __shared__ int sm[256];
  int i = blockIdx.x * 256 + threadIdx.x;
  int v = (i < n) ? cnt[i] : 0;
  if (i < n) dinv[i] = rsqrtf((float)(v + 1));  // +1 self-loop
  sm[threadIdx.x] = v;
  __syncthreads();
  for (int off = 128; off > 0; off >>= 1) {
    if (threadIdx.x < off) sm[threadIdx.x] += sm[threadIdx.x + off];
    __syncthreads();
  }
  if (threadIdx.x == 0) bsum[blockIdx.x] = sm[0];
}

// offsets: inline exclusive scan of bsum (nb<=256) + per-chunk scan + cur=0
__global__ __launch_bounds__(256) void scan_offsets(const int* __restrict__ cnt,
                                                    const int* __restrict__ bsum,
                                                    int* __restrict__ offs,
                                                    int* __restrict__ cur,
                                                    int n, int nb) {
  __shared__ int sm[256];
  int t = threadIdx.x;
  // pass 1: inclusive scan of bsum in LDS
  int bv = (t < nb) ? bsum[t] : 0;
  sm[t] = bv;
  __syncthreads();
  for (int off = 1; off < 256; off <<= 1) {
    int add = (t >= off) ? sm[t - off] : 0;
    __syncthreads();
    sm[t] += add;
    __syncthreads();
  }
  int bid = blockIdx.x;
  int base = (bid > 0) ? sm[bid - 1] : 0;  // exclusive prefix for this block
  __syncthreads();
  // pass 2: scan this block's 256-deg chunk
  int i = bid * 256 + t;
  int v = (i < n) ? cnt[i] : 0;
  sm[t] = v;
  __syncthreads();
  for (int off = 1; off < 256; off <<= 1) {
    int add = (t >= off) ? sm[t - off] : 0;
    __syncthreads();
    sm[t] += add;
    __syncthreads();
  }
  if (i < n) {
    offs[i] = base + sm[t] - v;
    cur[i] = 0;
  }
  if (i == n - 1) offs[n] = base + sm[t];  // total
}

__global__ __launch_bounds__(256) void fill_k(const int* __restrict__ src,
                                              const int* __restrict__ dst,
                                              const int* __restrict__ offs,
                                              int* __restrict__ cur,
                                              int* __restrict__ csr, int E) {
  int i = blockIdx.x * 256 + threadIdx.x;
  if (i >= E) return;
  int d = dst[i];
  int p = offs[d] + atomicAdd(&cur[d], 1);
  csr[p] = src[i];
}

// --- W1[384][128] & W2[128][128] fp32 -> Wt[128][K] bf16 (one launch) ---
__global__ __launch_bounds__(256) void prep_w_k(const float* __restrict__ W1,
                                                short* __restrict__ W1t,
                                                const float* __restrict__ W2,
                                                short* __restrict__ W2t) {
  int idx = blockIdx.x * 256 + threadIdx.x;
  if (idx < 384 * HID) {
    int k = idx >> 7;
    int c = idx & 127;
    W1t[(size_t)c * 384 + k] = f2bf(W1[idx]);
  } else if (idx < 384 * HID + HID * HID) {
    int j = idx - 384 * HID;
    int k = j >> 7;
    int c = j & 127;
    W2t[(size_t)c * HID + k] = f2bf(W2[j]);
  }
}

// --- bf16 MFMA GEMM: C[M][128] = bf16( (A[M][K] @ Wt^T) * scale[row] ) ---
// 64x128 tile, 4 waves (2x2 of 32x64), BK=64, mfma_f32_16x16x32_bf16.
template <int K, bool BF16SRC>
__global__ __launch_bounds__(256) void mfma_gemm_k(const void* __restrict__ Av,
                                                   const short* __restrict__ Wt,
                                                   const float* __restrict__ scale,
                                                   short* __restrict__ C, int M) {
  constexpr int BK = 64;
  constexpr int ROWE = BK + 8;  // 72 shorts = 144B rows (16B aligned)
  __shared__ short As[64 * ROWE];
  __shared__ short Bs[128 * ROWE];
  __shared__ float dln[64];

  const int tid = threadIdx.x;
  const int wave = tid >> 6;
  const int lane = tid & 63;
  const int l15 = lane & 15;
  const int lk = lane >> 4;          // k-group 0..3
  const int mh = (wave >> 1) * 32;   // wave row offset in tile
  const int nh = (wave & 1) * 64;    // wave col offset
  const int row0 = blockIdx.x * 64;

  if (tid < 64) {
    int r = row0 + tid;
    dln[tid] = (r < M) ? scale[r] : 0.f;
  }

  f32x4 acc[2][4] = {};

  for (int k0 = 0; k0 < K; k0 += BK) {
    __syncthreads();  // previous iter's LDS reads done before overwrite
    if (BF16SRC) {
      const short* Ab = (const short*)Av;
#pragma unroll
      for (int it = 0; it < 2; ++it) {
        int f = tid + it * 256;
        int r = f >> 3;
        int kc = (f & 7) << 3;
        int gr = row0 + r;
        bf16x8 v = {};
        if (gr < M) v = *(const bf16x8*)&Ab[(size_t)gr * K + k0 + kc];
        *(bf16x8*)&As[r * ROWE + kc] = v;
      }
    } else {
      const float* Af = (const float*)Av;
#pragma unroll
      for (int it = 0; it < 4; ++it) {
        int f = tid + it * 256;
        int r = f >> 4;
        int kc = (f & 15) << 2;
        int gr = row0 + r;
        float4 v = make_float4(0.f, 0.f, 0.f, 0.f);
        if (gr < M) v = *(const float4*)&Af[(size_t)gr * K + k0 + kc];
        bf16x4 s;
        s[0] = f2bf(v.x); s[1] = f2bf(v.y); s[2] = f2bf(v.z); s[3] = f2bf(v.w);
        *(bf16x4*)&As[r * ROWE + kc] = s;
      }
    }
#pragma unroll
    for (int it = 0; it < 4; ++it) {
      int f = tid + it * 256;
      int r = f >> 3;
      int kc = (f & 7) << 3;
      *(bf16x8*)&Bs[r * ROWE + kc] =
          *(const bf16x8*)&Wt[(size_t)r * K + k0 + kc];
    }
    __syncthreads();
#pragma unroll
    for (int ks = 0; ks < 2; ++ks) {
      bf16x8 af[2], bfr[4];
#pragma unroll
      for (int mf = 0; mf < 2; ++mf)
        af[mf] = *(const bf16x8*)&As[(mh + mf * 16 + l15) * ROWE + ks * 32 + lk * 8];
#pragma unroll
      for (int nf = 0; nf < 4; ++nf)
        bfr[nf] = *(const bf16x8*)&Bs[(nh + nf * 16 + l15) * ROWE + ks * 32 + lk * 8];
#pragma unroll
      for (int mf = 0; mf < 2; ++mf)
#pragma unroll
        for (int nf = 0; nf < 4; ++nf)
          acc[mf][nf] = __builtin_amdgcn_mfma_f32_16x16x32_bf16(
              af[mf], bfr[nf], acc[mf][nf], 0, 0, 0);
    }
  }
  // epilogue: C/D layout col=lane&15, row=(lane>>4)*4+reg
#pragma unroll
  for (int mf = 0; mf < 2; ++mf) {
#pragma unroll
    for (int r = 0; r < 4; ++r) {
      int lr = mh + mf * 16 + lk * 4 + r;
      int gr = row0 + lr;
      if (gr >= M) continue;
      float s = dln[lr];
#pragma unroll
      for (int nf = 0; nf < 4; ++nf)
        C[(size_t)gr * HID + nh + nf * 16 + l15] = f2bf(acc[mf][nf][r] * s);
    }
  }
}

// --- aggregation: out[v] = bf16(relu(dinv[v]*(sum_in Hs[u] + Hs[v]) + b))
// Hs bf16. 16 lanes/node, bf16x8 (16B) per lane, edge unroll x4:
// 4 rows (64B/lane) outstanding -> memory-level parallelism vs latency.
__global__ __launch_bounds__(256) void agg_k(const short* __restrict__ Hs,
                                             const int* __restrict__ offs,
                                             const int* __restrict__ csr,
                                             const float* __restrict__ dinv,
                                             const float* __restrict__ bias,
                                             short* __restrict__ out, int N) {
  int grp = threadIdx.x >> 4;          // 16 groups of 16 lanes
  int lane = threadIdx.x & 15;         // lane owns 8 consecutive bf16
  int v = blockIdx.x * 16 + grp;
  if (v >= N) return;
  int s = offs[v];
  int e = offs[v + 1];
  int c0 = lane << 3;
  bf16x8 sv = *(const bf16x8*)&Hs[(size_t)v * HID + c0];
  float a[8];
#pragma unroll
  for (int q = 0; q < 8; ++q) a[q] = bf2f(sv[q]);
  int p = s;
  for (; p + 4 <= e; p += 4) {
    int u0 = csr[p + 0];
    int u1 = csr[p + 1];
    int u2 = csr[p + 2];
    int u3 = csr[p + 3];
    bf16x8 x0 = *(const bf16x8*)&Hs[(size_t)u0 * HID + c0];
    bf16x8 x1 = *(const bf16x8*)&Hs[(size_t)u1 * HID + c0];
    bf16x8 x2 = *(const bf16x8*)&Hs[(size_t)u2 * HID + c0];
    bf16x8 x3 = *(const bf16x8*)&Hs[(size_t)u3 * HID + c0];
#pragma unroll
    for (int q = 0; q < 8; ++q)
      a[q] += (bf2f(x0[q]) + bf2f(x1[q])) + (bf2f(x2[q]) + bf2f(x3[q]));
  }
  for (; p < e; ++p) {
    int u = csr[p];
    bf16x8 x = *(const bf16x8*)&Hs[(size_t)u * HID + c0];
#pragma unroll
    for (int q = 0; q < 8; ++q) a[q] += bf2f(x[q]);
  }
  float dv = dinv[v];
  float4 b0 = *(const float4*)&bias[c0];
  float4 b1 = *(const float4*)&bias[c0 + 4];
  float bb[8] = {b0.x, b0.y, b0.z, b0.w, b1.x, b1.y, b1.z, b1.w};
  bf16x8 o;
#pragma unroll
  for (int q = 0; q < 8; ++q)
    o[q] = f2bf(fmaxf(fmaf(a[q], dv, bb[q]), 0.f));
  *(bf16x8*)&out[(size_t)v * HID + c0] = o;
}

// --- parallel mean-pool stage 1: per-chunk segmented column sums (bf16 in) ---
__global__ __launch_bounds__(256) void pool_sums_k(const short* __restrict__ G,
                                                   const int* __restrict__ batch,
                                                   float* __restrict__ sums, int n) {
  __shared__ int bsm[256];
  int r0 = blockIdx.x * 256;
  int rend = min(r0 + 256, n);
  int cnt = rend - r0;
  int t = threadIdx.x;
  if (t < cnt) bsm[t] = batch[r0 + t];
  __syncthreads();
  int j = t & 127;
  int h = t >> 7;
  if (h >= cnt) return;
  int g_cur = bsm[h];
  float acc = 0.f;
  for (int rr = h; rr < cnt; rr += 2) {
    int g = bsm[rr];
    if (g != g_cur) {
      atomicAdd(&sums[(size_t)g_cur * HID + j], acc);
      acc = 0.f;
      g_cur = g;
    }
    acc += bf2f(G[(size_t)(r0 + rr) * HID + j]);
  }
  atomicAdd(&sums[(size_t)g_cur * HID + j], acc);
}

// --- head: pooled = sums/cnt; fused = relu([seq|pooled] @ Wf + bf); outputs ---
__global__ __launch_bounds__(128) void head_k(const float* __restrict__ seq,
                                              const float* __restrict__ sums,
                                              const int* __restrict__ batch,
                                              const float* __restrict__ Wf,
                                              const float* __restrict__ bf,
                                              const float* __restrict__ Wtp,
                                              const float* __restrict__ btp,
                                              const float* __restrict__ Wp,
                                              const float* __restrict__ bp,
                                              float* __restrict__ outp,
                                              int B, int SEQ, int n) {
  int g = blockIdx.x;
  int t = threadIdx.x;
  __shared__ float xin[512];
  __shared__ float fs[128];
  int lo = 0, hi = n;
  while (lo < hi) { int mid = (lo + hi) >> 1; if (batch[mid] < g) lo = mid + 1; else hi = mid; }
  int start = lo;
  hi = n;
  while (lo < hi) { int mid = (lo + hi) >> 1; if (batch[mid] <= g) lo = mid + 1; else hi = mid; }
  float inv_cnt = 1.f / fmaxf((float)(lo - start), 1.f);
  for (int i = t; i < SEQ; i += 128) xin[i] = seq[(size_t)g * SEQ + i];
  xin[SEQ + t] = sums[g * HID + t] * inv_cnt;
  __syncthreads();
  float acc = bf[t];
#pragma unroll 8
  for (int k = 0; k < 512; ++k) acc = fmaf(xin[k], Wf[(size_t)k * HID + t], acc);
  fs[t] = fmaxf(acc, 0.f);
  __syncthreads();
  if (t == 0) {
    float a0 = btp[0], a1 = btp[1], a2 = bp[0];
    for (int k = 0; k < 128; ++k) {
      float f = fs[k];
      a0 = fmaf(f, Wtp[k * 2 + 0], a0);
      a1 = fmaf(f, Wtp[k * 2 + 1], a1);
      a2 = fmaf(f, Wp[k], a2);
    }
    outp[g * 2 + 0] = a0;
    outp[g * 2 + 1] = a1;
    outp[B * 2 + g] = a2;
  }
}

extern "C" void kernel_launch(void* const* d_in, const int* in_sizes, int n_in,
                              void* d_out, int out_size, void* d_ws, size_t ws_size,
                              hipStream_t stream) {
  const float* seq_emb = (const float*)d_in[0];
  const float* node_x  = (const float*)d_in[1];
  const int*   eidx    = (const int*)d_in[2];
  const int*   nbatch  = (const int*)d_in[3];
  const float* W1  = (const float*)d_in[4];
  const float* b1  = (const float*)d_in[5];
  const float* W2  = (const float*)d_in[6];
  const float* b2  = (const float*)d_in[7];
  const float* Wf  = (const float*)d_in[8];
  const float* bfb = (const float*)d_in[9];
  const float* Wtp = (const float*)d_in[10];
  const float* btp = (const float*)d_in[11];
  const float* Wp  = (const float*)d_in[12];
  const float* bp  = (const float*)d_in[13];

  const int N = in_sizes[3];           // 50000 nodes
  const int E = in_sizes[2] / 2;       // 600000 edges
  const int SEQ = 384;
  const int B = in_sizes[0] / SEQ;     // 64 graphs

  char* w = (char*)d_ws;
  auto alloc = [&](size_t bytes) -> void* {
    void* p = (void*)w;
    w += (bytes + 255) & ~(size_t)255;
    return p;
  };
  float* dinv   = (float*)alloc((size_t)N * 4);
  int*   deg    = (int*)alloc((size_t)N * 4);
  int*   cur    = (int*)alloc((size_t)N * 4);
  int*   offs   = (int*)alloc((size_t)(N + 1) * 4);
  int*   bsum   = (int*)alloc(1024);
  int*   csr    = (int*)alloc((size_t)E * 4);
  short* W1t    = (short*)alloc((size_t)SEQ * HID * 2);
  short* W2t    = (short*)alloc((size_t)HID * HID * 2);
  short* bufC   = (short*)alloc((size_t)N * HID * 2);   // Hs bf16
  short* bufG   = (short*)alloc((size_t)N * HID * 2);   // g bf16
  float* sums   = (float*)alloc((size_t)B * HID * 4);

  const int* srcp = eidx;
  const int* dstp = eidx + E;

  hipMemsetAsync(deg, 0, (size_t)N * 4, stream);
  hipMemsetAsync(sums, 0, (size_t)B * HID * 4, stream);

  int gE = (E + 255) / 256;
  int gN = (N + 255) / 256;  // 196 <= 256 (required by inline bsum scan)
  hist_k<<<gE, 256, 0, stream>>>(dstp, deg, E);
  scan_bsum<<<gN, 256, 0, stream>>>(deg, bsum, dinv, N);
  scan_offsets<<<gN, 256, 0, stream>>>(deg, bsum, offs, cur, N, gN);
  fill_k<<<gE, 256, 0, stream>>>(srcp, dstp, offs, cur, csr, E);

  prep_w_k<<<(SEQ * HID + HID * HID + 255) / 256, 256, 0, stream>>>(W1, W1t, W2, W2t);

  int gG = (N + 63) / 64;
  int gA = (N + 15) / 16;
  mfma_gemm_k<384, false><<<gG, 256, 0, stream>>>(node_x, W1t, dinv, bufC, N);
  agg_k<<<gA, 256, 0, stream>>>(bufC, offs, csr, dinv, b1, bufG, N);
  mfma_gemm_k<128, true><<<gG, 256, 0, stream>>>(bufG, W2t, dinv, bufC, N);
  agg_k<<<gA, 256, 0, stream>>>(bufC, offs, csr, dinv, b2, bufG, N);
  pool_sums_k<<<gN, 256, 0, stream>>>(bufG, nbatch, sums, N);
  head_k<<<B, 128, 0, stream>>>(seq_emb, sums, nbatch, Wf, bfb, Wtp, btp, Wp, bp,
                                (float*)d_out, B, SEQ, N);
}

// Round 7
// 229.811 us; speedup vs baseline: 2.3691x; 1.0051x over previous
//
#include <hip/hip_runtime.h>

// ---------------------------------------------------------------------------
// 2-layer GCN + mean-pool + MLP head.
// R4: bf16 MFMA GEMMs, Hs bf16. R5: 64x128 GEMM tile, agg/pool bf16.
// R6: agg 16 lanes/node x bf16x8, launch diet (13 dispatches).
// R7: launch diet II (11 dispatches: deg-zero in prep_w, sums-zero in
//     scan_offsets); agg edge-unroll x8 (128B/lane in flight).
// ---------------------------------------------------------------------------

#define HID 128

typedef __attribute__((ext_vector_type(8))) short bf16x8;
typedef __attribute__((ext_vector_type(4))) short bf16x4;
typedef __attribute__((ext_vector_type(4))) float f32x4;

static __device__ __forceinline__ short f2bf(float f) {
  union { float f; unsigned u; } v; v.f = f;
  unsigned r = v.u + 0x7fff + ((v.u >> 16) & 1);  // RNE
  return (short)(r >> 16);
}
static __device__ __forceinline__ float bf2f(short s) {
  union { unsigned u; float f; } v;
  v.u = ((unsigned)(unsigned short)s) << 16;
  return v.f;
}

// --- W1/W2 fp32 -> Wt bf16 (transpose + convert) + zero deg (fused) ---
__global__ __launch_bounds__(256) void prep_w_k(const float* __restrict__ W1,
                                                short* __restrict__ W1t,
                                                const float* __restrict__ W2,
                                                short* __restrict__ W2t,
                                                int* __restrict__ deg, int N) {
  int idx = blockIdx.x * 256 + threadIdx.x;
  if (idx < 384 * HID) {
    int k = idx >> 7;
    int c = idx & 127;
    W1t[(size_t)c * 384 + k] = f2bf(W1[idx]);
  } else if (idx < 384 * HID + HID * HID) {
    int j = idx - 384 * HID;
    int k = j >> 7;
    int c = j & 127;
    W2t[(size_t)c * HID + k] = f2bf(W2[j]);
  }
  if (idx < N) deg[idx] = 0;
}

__global__ __launch_bounds__(256) void hist_k(const int* __restrict__ dst,
                                              int* __restrict__ cnt, int E) {
  int i = blockIdx.x * 256 + threadIdx.x;
  if (i < E) atomicAdd(&cnt[dst[i]], 1);
}

// per-256-chunk sums of deg + dinv computation (fused)
__global__ __launch_bounds__(256) void scan_bsum(const int* __restrict__ cnt,
                                                 int* __restrict__ bsum,
                                                 float* __restrict__ dinv, int n) {
  __shared__ int sm[256];
  int i = blockIdx.x * 256 + threadIdx.x;
  int v = (i < n) ? cnt[i] : 0;
  if (i < n) dinv[i] = rsqrtf((float)(v + 1));  // +1 self-loop
  sm[threadIdx.x] = v;
  __syncthreads();
  for (int off = 128; off > 0; off >>= 1) {
    if (threadIdx.x < off) sm[threadIdx.x] += sm[threadIdx.x + off];
    __syncthreads();
  }
  if (threadIdx.x == 0) bsum[blockIdx.x] = sm[0];
}

// offsets: inline exclusive scan of bsum (nb<=256) + per-chunk scan
//          + cur=0 + sums=0 (fused zeroing)
__global__ __launch_bounds__(256) void scan_offsets(const int* __restrict__ cnt,
                                                    const int* __restrict__ bsum,
                                                    int* __restrict__ offs,
                                                    int* __restrict__ cur,
                                                    float* __restrict__ sums,
                                                    int nsum, int n, int nb) {
  __shared__ int sm[256];
  int t = threadIdx.x;
  int bid = blockIdx.x;
  int zi = bid * 256 + t;
  if (zi < nsum) sums[zi] = 0.f;
  // pass 1: inclusive scan of bsum in LDS
  int bv = (t < nb) ? bsum[t] : 0;
  sm[t] = bv;
  __syncthreads();
  for (int off = 1; off < 256; off <<= 1) {
    int add = (t >= off) ? sm[t - off] : 0;
    __syncthreads();
    sm[t] += add;
    __syncthreads();
  }
  int base = (bid > 0) ? sm[bid - 1] : 0;  // exclusive prefix for this block
  __syncthreads();
  // pass 2: scan this block's 256-deg chunk
  int i = bid * 256 + t;
  int v = (i < n) ? cnt[i] : 0;
  sm[t] = v;
  __syncthreads();
  for (int off = 1; off < 256; off <<= 1) {
    int add = (t >= off) ? sm[t - off] : 0;
    __syncthreads();
    sm[t] += add;
    __syncthreads();
  }
  if (i < n) {
    offs[i] = base + sm[t] - v;
    cur[i] = 0;
  }
  if (i == n - 1) offs[n] = base + sm[t];  // total
}

__global__ __launch_bounds__(256) void fill_k(const int* __restrict__ src,
                                              const int* __restrict__ dst,
                                              const int* __restrict__ offs,
                                              int* __restrict__ cur,
                                              int* __restrict__ csr, int E) {
  int i = blockIdx.x * 256 + threadIdx.x;
  if (i >= E) return;
  int d = dst[i];
  int p = offs[d] + atomicAdd(&cur[d], 1);
  csr[p] = src[i];
}

// --- bf16 MFMA GEMM: C[M][128] = bf16( (A[M][K] @ Wt^T) * scale[row] ) ---
// 64x128 tile, 4 waves (2x2 of 32x64), BK=64, mfma_f32_16x16x32_bf16.
template <int K, bool BF16SRC>
__global__ __launch_bounds__(256) void mfma_gemm_k(const void* __restrict__ Av,
                                                   const short* __restrict__ Wt,
                                                   const float* __restrict__ scale,
                                                   short* __restrict__ C, int M) {
  constexpr int BK = 64;
  constexpr int ROWE = BK + 8;  // 72 shorts = 144B rows (16B aligned)
  __shared__ short As[64 * ROWE];
  __shared__ short Bs[128 * ROWE];
  __shared__ float dln[64];

  const int tid = threadIdx.x;
  const int wave = tid >> 6;
  const int lane = tid & 63;
  const int l15 = lane & 15;
  const int lk = lane >> 4;          // k-group 0..3
  const int mh = (wave >> 1) * 32;   // wave row offset in tile
  const int nh = (wave & 1) * 64;    // wave col offset
  const int row0 = blockIdx.x * 64;

  if (tid < 64) {
    int r = row0 + tid;
    dln[tid] = (r < M) ? scale[r] : 0.f;
  }

  f32x4 acc[2][4] = {};

  for (int k0 = 0; k0 < K; k0 += BK) {
    __syncthreads();  // previous iter's LDS reads done before overwrite
    if (BF16SRC) {
      const short* Ab = (const short*)Av;
#pragma unroll
      for (int it = 0; it < 2; ++it) {
        int f = tid + it * 256;
        int r = f >> 3;
        int kc = (f & 7) << 3;
        int gr = row0 + r;
        bf16x8 v = {};
        if (gr < M) v = *(const bf16x8*)&Ab[(size_t)gr * K + k0 + kc];
        *(bf16x8*)&As[r * ROWE + kc] = v;
      }
    } else {
      const float* Af = (const float*)Av;
#pragma unroll
      for (int it = 0; it < 4; ++it) {
        int f = tid + it * 256;
        int r = f >> 4;
        int kc = (f & 15) << 2;
        int gr = row0 + r;
        float4 v = make_float4(0.f, 0.f, 0.f, 0.f);
        if (gr < M) v = *(const float4*)&Af[(size_t)gr * K + k0 + kc];
        bf16x4 s;
        s[0] = f2bf(v.x); s[1] = f2bf(v.y); s[2] = f2bf(v.z); s[3] = f2bf(v.w);
        *(bf16x4*)&As[r * ROWE + kc] = s;
      }
    }
#pragma unroll
    for (int it = 0; it < 4; ++it) {
      int f = tid + it * 256;
      int r = f >> 3;
      int kc = (f & 7) << 3;
      *(bf16x8*)&Bs[r * ROWE + kc] =
          *(const bf16x8*)&Wt[(size_t)r * K + k0 + kc];
    }
    __syncthreads();
#pragma unroll
    for (int ks = 0; ks < 2; ++ks) {
      bf16x8 af[2], bfr[4];
#pragma unroll
      for (int mf = 0; mf < 2; ++mf)
        af[mf] = *(const bf16x8*)&As[(mh + mf * 16 + l15) * ROWE + ks * 32 + lk * 8];
#pragma unroll
      for (int nf = 0; nf < 4; ++nf)
        bfr[nf] = *(const bf16x8*)&Bs[(nh + nf * 16 + l15) * ROWE + ks * 32 + lk * 8];
#pragma unroll
      for (int mf = 0; mf < 2; ++mf)
#pragma unroll
        for (int nf = 0; nf < 4; ++nf)
          acc[mf][nf] = __builtin_amdgcn_mfma_f32_16x16x32_bf16(
              af[mf], bfr[nf], acc[mf][nf], 0, 0, 0);
    }
  }
  // epilogue: C/D layout col=lane&15, row=(lane>>4)*4+reg
#pragma unroll
  for (int mf = 0; mf < 2; ++mf) {
#pragma unroll
    for (int r = 0; r < 4; ++r) {
      int lr = mh + mf * 16 + lk * 4 + r;
      int gr = row0 + lr;
      if (gr >= M) continue;
      float s = dln[lr];
#pragma unroll
      for (int nf = 0; nf < 4; ++nf)
        C[(size_t)gr * HID + nh + nf * 16 + l15] = f2bf(acc[mf][nf][r] * s);
    }
  }
}

// --- aggregation: out[v] = bf16(relu(dinv[v]*(sum_in Hs[u] + Hs[v]) + b))
// Hs bf16. 16 lanes/node, bf16x8 (16B) per lane, edge unroll x8/x4/x1:
// up to 8 rows (128B/lane) outstanding for memory-level parallelism.
__global__ __launch_bounds__(256) void agg_k(const short* __restrict__ Hs,
                                             const int* __restrict__ offs,
                                             const int* __restrict__ csr,
                                             const float* __restrict__ dinv,
                                             const float* __restrict__ bias,
                                             short* __restrict__ out, int N) {
  int grp = threadIdx.x >> 4;          // 16 groups of 16 lanes
  int lane = threadIdx.x & 15;         // lane owns 8 consecutive bf16
  int v = blockIdx.x * 16 + grp;
  if (v >= N) return;
  int s = offs[v];
  int e = offs[v + 1];
  int c0 = lane << 3;
  bf16x8 sv = *(const bf16x8*)&Hs[(size_t)v * HID + c0];
  float a[8];
#pragma unroll
  for (int q = 0; q < 8; ++q) a[q] = bf2f(sv[q]);
  int p = s;
  for (; p + 8 <= e; p += 8) {
    int u[8];
#pragma unroll
    for (int q = 0; q < 8; ++q) u[q] = csr[p + q];
    bf16x8 x[8];
#pragma unroll
    for (int q = 0; q < 8; ++q)
      x[q] = *(const bf16x8*)&Hs[(size_t)u[q] * HID + c0];
#pragma unroll
    for (int q = 0; q < 8; ++q)
#pragma unroll
      for (int r = 0; r < 8; ++r) a[r] += bf2f(x[q][r]);
  }
  for (; p + 4 <= e; p += 4) {
    int u0 = csr[p + 0];
    int u1 = csr[p + 1];
    int u2 = csr[p + 2];
    int u3 = csr[p + 3];
    bf16x8 x0 = *(const bf16x8*)&Hs[(size_t)u0 * HID + c0];
    bf16x8 x1 = *(const bf16x8*)&Hs[(size_t)u1 * HID + c0];
    bf16x8 x2 = *(const bf16x8*)&Hs[(size_t)u2 * HID + c0];
    bf16x8 x3 = *(const bf16x8*)&Hs[(size_t)u3 * HID + c0];
#pragma unroll
    for (int q = 0; q < 8; ++q)
      a[q] += (bf2f(x0[q]) + bf2f(x1[q])) + (bf2f(x2[q]) + bf2f(x3[q]));
  }
  for (; p < e; ++p) {
    int u = csr[p];
    bf16x8 x = *(const bf16x8*)&Hs[(size_t)u * HID + c0];
#pragma unroll
    for (int q = 0; q < 8; ++q) a[q] += bf2f(x[q]);
  }
  float dv = dinv[v];
  float4 b0 = *(const float4*)&bias[c0];
  float4 b1 = *(const float4*)&bias[c0 + 4];
  float bb[8] = {b0.x, b0.y, b0.z, b0.w, b1.x, b1.y, b1.z, b1.w};
  bf16x8 o;
#pragma unroll
  for (int q = 0; q < 8; ++q)
    o[q] = f2bf(fmaxf(fmaf(a[q], dv, bb[q]), 0.f));
  *(bf16x8*)&out[(size_t)v * HID + c0] = o;
}

// --- parallel mean-pool stage 1: per-chunk segmented column sums (bf16 in) ---
__global__ __launch_bounds__(256) void pool_sums_k(const short* __restrict__ G,
                                                   const int* __restrict__ batch,
                                                   float* __restrict__ sums, int n) {
  __shared__ int bsm[256];
  int r0 = blockIdx.x * 256;
  int rend = min(r0 + 256, n);
  int cnt = rend - r0;
  int t = threadIdx.x;
  if (t < cnt) bsm[t] = batch[r0 + t];
  __syncthreads();
  int j = t & 127;
  int h = t >> 7;
  if (h >= cnt) return;
  int g_cur = bsm[h];
  float acc = 0.f;
  for (int rr = h; rr < cnt; rr += 2) {
    int g = bsm[rr];
    if (g != g_cur) {
      atomicAdd(&sums[(size_t)g_cur * HID + j], acc);
      acc = 0.f;
      g_cur = g;
    }
    acc += bf2f(G[(size_t)(r0 + rr) * HID + j]);
  }
  atomicAdd(&sums[(size_t)g_cur * HID + j], acc);
}

// --- head: pooled = sums/cnt; fused = relu([seq|pooled] @ Wf + bf); outputs ---
__global__ __launch_bounds__(128) void head_k(const float* __restrict__ seq,
                                              const float* __restrict__ sums,
                                              const int* __restrict__ batch,
                                              const float* __restrict__ Wf,
                                              const float* __restrict__ bf,
                                              const float* __restrict__ Wtp,
                                              const float* __restrict__ btp,
                                              const float* __restrict__ Wp,
                                              const float* __restrict__ bp,
                                              float* __restrict__ outp,
                                              int B, int SEQ, int n) {
  int g = blockIdx.x;
  int t = threadIdx.x;
  __shared__ float xin[512];
  __shared__ float fs[128];
  int lo = 0, hi = n;
  while (lo < hi) { int mid = (lo + hi) >> 1; if (batch[mid] < g) lo = mid + 1; else hi = mid; }
  int start = lo;
  hi = n;
  while (lo < hi) { int mid = (lo + hi) >> 1; if (batch[mid] <= g) lo = mid + 1; else hi = mid; }
  float inv_cnt = 1.f / fmaxf((float)(lo - start), 1.f);
  for (int i = t; i < SEQ; i += 128) xin[i] = seq[(size_t)g * SEQ + i];
  xin[SEQ + t] = sums[g * HID + t] * inv_cnt;
  __syncthreads();
  float acc = bf[t];
#pragma unroll 8
  for (int k = 0; k < 512; ++k) acc = fmaf(xin[k], Wf[(size_t)k * HID + t], acc);
  fs[t] = fmaxf(acc, 0.f);
  __syncthreads();
  if (t == 0) {
    float a0 = btp[0], a1 = btp[1], a2 = bp[0];
    for (int k = 0; k < 128; ++k) {
      float f = fs[k];
      a0 = fmaf(f, Wtp[k * 2 + 0], a0);
      a1 = fmaf(f, Wtp[k * 2 + 1], a1);
      a2 = fmaf(f, Wp[k], a2);
    }
    outp[g * 2 + 0] = a0;
    outp[g * 2 + 1] = a1;
    outp[B * 2 + g] = a2;
  }
}

extern "C" void kernel_launch(void* const* d_in, const int* in_sizes, int n_in,
                              void* d_out, int out_size, void* d_ws, size_t ws_size,
                              hipStream_t stream) {
  const float* seq_emb = (const float*)d_in[0];
  const float* node_x  = (const float*)d_in[1];
  const int*   eidx    = (const int*)d_in[2];
  const int*   nbatch  = (const int*)d_in[3];
  const float* W1  = (const float*)d_in[4];
  const float* b1  = (const float*)d_in[5];
  const float* W2  = (const float*)d_in[6];
  const float* b2  = (const float*)d_in[7];
  const float* Wf  = (const float*)d_in[8];
  const float* bfb = (const float*)d_in[9];
  const float* Wtp = (const float*)d_in[10];
  const float* btp = (const float*)d_in[11];
  const float* Wp  = (const float*)d_in[12];
  const float* bp  = (const float*)d_in[13];

  const int N = in_sizes[3];           // 50000 nodes
  const int E = in_sizes[2] / 2;       // 600000 edges
  const int SEQ = 384;
  const int B = in_sizes[0] / SEQ;     // 64 graphs

  char* w = (char*)d_ws;
  auto alloc = [&](size_t bytes) -> void* {
    void* p = (void*)w;
    w += (bytes + 255) & ~(size_t)255;
    return p;
  };
  float* dinv   = (float*)alloc((size_t)N * 4);
  int*   deg    = (int*)alloc((size_t)N * 4);
  int*   cur    = (int*)alloc((size_t)N * 4);
  int*   offs   = (int*)alloc((size_t)(N + 1) * 4);
  int*   bsum   = (int*)alloc(1024);
  int*   csr    = (int*)alloc((size_t)E * 4);
  short* W1t    = (short*)alloc((size_t)SEQ * HID * 2);
  short* W2t    = (short*)alloc((size_t)HID * HID * 2);
  short* bufC   = (short*)alloc((size_t)N * HID * 2);   // Hs bf16
  short* bufG   = (short*)alloc((size_t)N * HID * 2);   // g bf16
  float* sums   = (float*)alloc((size_t)B * HID * 4);

  const int* srcp = eidx;
  const int* dstp = eidx + E;

  int gE = (E + 255) / 256;
  int gN = (N + 255) / 256;  // 196 <= 256 (required by inline bsum scan)
  int wElems = SEQ * HID + HID * HID;
  int gP = (max(wElems, N) + 255) / 256;

  prep_w_k<<<gP, 256, 0, stream>>>(W1, W1t, W2, W2t, deg, N);
  hist_k<<<gE, 256, 0, stream>>>(dstp, deg, E);
  scan_bsum<<<gN, 256, 0, stream>>>(deg, bsum, dinv, N);
  scan_offsets<<<gN, 256, 0, stream>>>(deg, bsum, offs, cur, sums, B * HID, N, gN);
  fill_k<<<gE, 256, 0, stream>>>(srcp, dstp, offs, cur, csr, E);

  int gG = (N + 63) / 64;
  int gA = (N + 15) / 16;
  mfma_gemm_k<384, false><<<gG, 256, 0, stream>>>(node_x, W1t, dinv, bufC, N);
  agg_k<<<gA, 256, 0, stream>>>(bufC, offs, csr, dinv, b1, bufG, N);
  mfma_gemm_k<128, true><<<gG, 256, 0, stream>>>(bufG, W2t, dinv, bufC, N);
  agg_k<<<gA, 256, 0, stream>>>(bufC, offs, csr, dinv, b2, bufG, N);
  pool_sums_k<<<gN, 256, 0, stream>>>(bufG, nbatch, sums, N);
  head_k<<<B, 128, 0, stream>>>(seq_emb, sums, nbatch, Wf, bfb, Wtp, btp, Wp, bp,
                                (float*)d_out, B, SEQ, N);
}